// Round 4
// baseline (3476.144 us; speedup 1.0000x reference)
//
#include <hip/hip_runtime.h>
#include <hip/hip_bf16.h>
#include <math.h>

#define NN 50000
#define NE 400000
#define HD 128
#define NB 64
#define NCH 8
#define CN 6250          // nodes per chunk
#define ECM 53248        // max edges per chunk
#define PSL 16           // pool slices

typedef __hip_bfloat16 bf16;
typedef __attribute__((ext_vector_type(4))) unsigned short us4;
typedef __attribute__((ext_vector_type(8))) short s8v;    // 8 bf16 MFMA frag
typedef __attribute__((ext_vector_type(4))) float f4v;    // MFMA accumulator

__device__ __forceinline__ float sigm_(float x){ return 1.f/(1.f+__expf(-x)); }
__device__ __forceinline__ float silu_(float x){ return x*sigm_(x); }
__device__ __forceinline__ float bf2f(bf16 x){ return __bfloat162float(x); }
__device__ __forceinline__ unsigned short f2bu(float f){
    bf16 h = __float2bfloat16(f);
    return *reinterpret_cast<unsigned short*>(&h);
}
__device__ __forceinline__ bool finite_(float v){ return fabsf(v) <= 1e37f; }

enum { M_PLAIN=0, M_BIAS, M_BNSILU };

// ---------------- split-transpose weight prep ----------------
__global__ void wprep(const float* __restrict__ W, bf16* __restrict__ H, bf16* __restrict__ L){
    int i = blockIdx.x*256 + threadIdx.x;
    int k = i >> 7, n = i & 127;
    float w = W[i];
    bf16 h = __float2bfloat16(w);
    float r = w - bf2f(h);
    H[n*128 + k] = h;
    L[n*128 + k] = __float2bfloat16(r);
}

__global__ void wprep1(const float* __restrict__ W, bf16* __restrict__ H, bf16* __restrict__ L){
    int i = blockIdx.x*256 + threadIdx.x;
    int n = i >> 6, k = i & 63;
    float w = (k < 41) ? W[(size_t)k*HD + n] : 0.f;
    bf16 h = __float2bfloat16(w);
    float r = w - bf2f(h);
    H[n*64 + k] = h;
    L[n*64 + k] = __float2bfloat16(r);
}

// ---------------- generic tiled GEMM ----------------
template<int MODE>
__global__ __launch_bounds__(256)
void gemmk(const float* __restrict__ A, const float* __restrict__ W,
           const float* __restrict__ bias, const float* __restrict__ gg,
           const float* __restrict__ be, void* __restrict__ Cv, int owf, int M, int K)
{
    const int row0 = blockIdx.x * 64;
    if (row0 >= M) return;
    __shared__ float As[32][68];
    __shared__ float Ws[32][128];
    const int tid = threadIdx.x;
    const int tx = tid & 15, ty = tid >> 4;
    const int col0 = tx*8;
    float acc[4][8];
#pragma unroll
    for (int r=0;r<4;++r)
#pragma unroll
        for (int j=0;j<8;++j) acc[r][j]=0.f;
    const int mload = tid >> 2;
    const int kload = (tid & 3) << 3;
    const int grow = row0 + mload;
    const bool rv = grow < M;

    for (int k0 = 0; k0 < K; k0 += 32) {
        if (rv && ((K & 3) == 0) && (k0 + kload + 8 <= K)) {
            const float* ap = A + (size_t)grow*K + k0 + kload;
            float4 v0 = *(const float4*)ap;
            float4 v1 = *(const float4*)(ap+4);
            As[kload+0][mload]=v0.x; As[kload+1][mload]=v0.y;
            As[kload+2][mload]=v0.z; As[kload+3][mload]=v0.w;
            As[kload+4][mload]=v1.x; As[kload+5][mload]=v1.y;
            As[kload+6][mload]=v1.z; As[kload+7][mload]=v1.w;
        } else {
#pragma unroll
            for (int j=0;j<8;++j){
                int kg = k0 + kload + j;
                As[kload+j][mload] = (rv && kg<K) ? A[(size_t)grow*K+kg] : 0.f;
            }
        }
        if (k0 + 32 <= K) {
#pragma unroll
            for (int j=0;j<4;++j){
                int el = (tid + j*256)*4;
                int kk = el >> 7, col = el & 127;
                *(float4*)&Ws[kk][col] = *(const float4*)&W[(size_t)(k0+kk)*HD + col];
            }
        } else {
#pragma unroll
            for (int j=0;j<16;++j){
                int el = tid*16 + j;
                int kk = el >> 7, col = el & 127;
                int kg = k0 + kk;
                Ws[kk][col] = (kg < K) ? W[(size_t)kg*HD + col] : 0.f;
            }
        }
        __syncthreads();
#pragma unroll
        for (int k=0;k<32;++k){
            float4 a4 = *(const float4*)&As[k][ty*4];
            float4 w0 = *(const float4*)&Ws[k][col0];
            float4 w1 = *(const float4*)&Ws[k][col0+4];
            float av[4] = {a4.x,a4.y,a4.z,a4.w};
            float wv[8] = {w0.x,w0.y,w0.z,w0.w,w1.x,w1.y,w1.z,w1.w};
#pragma unroll
            for (int r=0;r<4;++r)
#pragma unroll
                for (int j=0;j<8;++j) acc[r][j] += av[r]*wv[j];
        }
        __syncthreads();
    }
#pragma unroll
    for (int r=0;r<4;++r){
        int orow = row0 + ty*4 + r;
        if (orow >= M) continue;
        float o[8];
#pragma unroll
        for (int j=0;j<8;++j) o[j]=acc[r][j];
        if constexpr (MODE==M_BIAS || MODE==M_BNSILU){
#pragma unroll
            for (int j=0;j<8;++j) o[j] += bias[col0+j];
        }
        if constexpr (MODE==M_BNSILU){
#pragma unroll
            for (int j=0;j<8;++j) o[j] = silu_(o[j]*gg[col0+j] + be[col0+j]);
        }
        if (owf){
            bf16* C = (bf16*)Cv;
#pragma unroll
            for (int j=0;j<8;++j) C[(size_t)orow*HD+col0+j] = __float2bfloat16(o[j]);
        } else {
            float* C = (float*)Cv;
            float4* cp = (float4*)&C[(size_t)orow*HD + col0];
            cp[0] = make_float4(o[0],o[1],o[2],o[3]);
            cp[1] = make_float4(o[4],o[5],o[6],o[7]);
        }
    }
}

// ---------------- fused 3-GEMM (K=128, f32, no bias) for the nu stage ----------------
__global__ __launch_bounds__(256)
void gemm3(const float* __restrict__ A0, const float* __restrict__ W0, float* __restrict__ C0, int M0,
           const float* __restrict__ A1, const float* __restrict__ W1, float* __restrict__ C1, int M1,
           const float* __restrict__ A2, const float* __restrict__ W2, float* __restrict__ C2, int M2)
{
    const int nb0 = (M0+63)>>6, nb1 = (M1+63)>>6;
    int bb = (int)blockIdx.x;
    const float *A, *W; float* C; int M;
    if (bb < nb0){ A=A0; W=W0; C=C0; M=M0; }
    else if (bb < nb0+nb1){ bb -= nb0; A=A1; W=W1; C=C1; M=M1; }
    else { bb -= nb0+nb1; A=A2; W=W2; C=C2; M=M2; }
    const int row0 = bb*64;

    __shared__ float As[32][68];
    __shared__ float Ws[32][128];
    const int tid = threadIdx.x;
    const int tx = tid & 15, ty = tid >> 4;
    const int col0 = tx*8;
    float acc[4][8];
#pragma unroll
    for (int r=0;r<4;++r)
#pragma unroll
        for (int j=0;j<8;++j) acc[r][j]=0.f;
    const int mload = tid >> 2;
    const int kload = (tid & 3) << 3;
    const int grow = row0 + mload;
    const bool rv = grow < M;

    for (int k0 = 0; k0 < 128; k0 += 32) {
        if (rv) {
            const float* ap = A + (size_t)grow*128 + k0 + kload;
            float4 v0 = *(const float4*)ap;
            float4 v1 = *(const float4*)(ap+4);
            As[kload+0][mload]=v0.x; As[kload+1][mload]=v0.y;
            As[kload+2][mload]=v0.z; As[kload+3][mload]=v0.w;
            As[kload+4][mload]=v1.x; As[kload+5][mload]=v1.y;
            As[kload+6][mload]=v1.z; As[kload+7][mload]=v1.w;
        } else {
#pragma unroll
            for (int j=0;j<8;++j) As[kload+j][mload] = 0.f;
        }
#pragma unroll
        for (int j=0;j<4;++j){
            int el = (tid + j*256)*4;
            int kk = el >> 7, col = el & 127;
            *(float4*)&Ws[kk][col] = *(const float4*)&W[(size_t)(k0+kk)*HD + col];
        }
        __syncthreads();
#pragma unroll
        for (int k=0;k<32;++k){
            float4 a4 = *(const float4*)&As[k][ty*4];
            float4 w0 = *(const float4*)&Ws[k][col0];
            float4 w1 = *(const float4*)&Ws[k][col0+4];
            float av[4] = {a4.x,a4.y,a4.z,a4.w};
            float wv[8] = {w0.x,w0.y,w0.z,w0.w,w1.x,w1.y,w1.z,w1.w};
#pragma unroll
            for (int r=0;r<4;++r)
#pragma unroll
                for (int j=0;j<8;++j) acc[r][j] += av[r]*wv[j];
        }
        __syncthreads();
    }
#pragma unroll
    for (int r=0;r<4;++r){
        int orow = row0 + ty*4 + r;
        if (orow >= M) continue;
        float4* cp = (float4*)&C[(size_t)orow*HD + col0];
        cp[0] = make_float4(acc[r][0],acc[r][1],acc[r][2],acc[r][3]);
        cp[1] = make_float4(acc[r][4],acc[r][5],acc[r][6],acc[r][7]);
    }
}

// ---------------- MFMA fused edge pipeline ----------------
// LDS-staged gathers: eat rows staged into T2-as-float (G1); An/Bn rows staged
// into T2 during phase 1's dead window. All global reads coalesced.
__global__ __launch_bounds__(256)
void edge_pipe(const float* __restrict__ eat,
               const int* __restrict__ elist, const int* __restrict__ srcp,
               const int* __restrict__ dstp,
               const bf16* __restrict__ W1h, const bf16* __restrict__ W1l,
               const float* __restrict__ b1,
               const bf16* __restrict__ W2h, const bf16* __restrict__ W2l,
               const float* __restrict__ b2,
               const bf16* __restrict__ Wmeh, const bf16* __restrict__ Wmel,
               const float* __restrict__ bm,
               const bf16* __restrict__ An, const bf16* __restrict__ Bn,
               const bf16* __restrict__ Wv1h, const bf16* __restrict__ Wv1l,
               const float* __restrict__ bv1,
               const int* __restrict__ rp, int rn0, int rn1,
               bf16* __restrict__ outM, bf16* __restrict__ outG)
{
    __shared__ __align__(16) unsigned short T1[64][136];
    __shared__ __align__(16) unsigned short T2[64][136];   // also used as float[64][68]
    __shared__ int elS[64], seS[64], deS[64];

    const int cbase = rp[rn0];
    const int Ml = min(ECM, max(rp[rn1]-cbase, 0));
    const int row0 = blockIdx.x*64;
    if (row0 >= Ml) return;
    const int tid = threadIdx.x;
    const int lane = tid & 63, wave = tid >> 6;
    const int quad = lane >> 4, n16 = lane & 15;
    const int cwb = wave*32;

    if (tid < 64){
        int r = row0 + tid;
        bool v = r < Ml;
        int p = cbase + (v ? r : 0);
        elS[tid] = v ? min(max(elist[p],0),NE-1) : 0;
        seS[tid] = v ? srcp[p] : 0;
        deS[tid] = v ? dstp[p] : 0;
    }
    __syncthreads();

    f4v acc[4][2];
    float (*Ef)[68] = (float(*)[68])T2;   // 64x68 f32 == 64x136 ushort (17408 B)

    // ---------- G1: K=64(padded) split MFMA, eat staged via LDS ----------
    {
        // coalesced stage: wave covers one eat row (41 floats) at a time
#pragma unroll
        for (int it=0; it<16; ++it){
            int idx = tid + it*256;          // 0..4095
            int r = idx >> 6, k = idx & 63;
            float v = 0.f;
            if (k < 41) v = eat[(size_t)elS[r]*41 + k];
            Ef[r][k] = v;
        }

        s8v B1h[2][2], B1l[2][2];
#pragma unroll
        for (int ct=0; ct<2; ++ct){
            int nn = cwb + ct*16 + n16;
#pragma unroll
            for (int kc=0; kc<2; ++kc){
                B1h[ct][kc] = *(const s8v*)&W1h[(size_t)nn*64 + kc*32 + quad*8];
                B1l[ct][kc] = *(const s8v*)&W1l[(size_t)nn*64 + kc*32 + quad*8];
            }
        }
#pragma unroll
        for (int rt=0;rt<4;++rt)
#pragma unroll
            for (int ct=0;ct<2;++ct) acc[rt][ct] = (f4v){0.f,0.f,0.f,0.f};

        __syncthreads();   // staging complete

#pragma unroll
        for (int rt=0; rt<4; ++rt){
            const int arow = rt*16 + n16;
#pragma unroll
            for (int kc=0; kc<2; ++kc){
                const float* ep = &Ef[arow][kc*32 + quad*8];
                float4 v0 = *(const float4*)ep;
                float4 v1 = *(const float4*)(ep+4);
                float vv[8] = {v0.x,v0.y,v0.z,v0.w,v1.x,v1.y,v1.z,v1.w};
                s8v ah, al;
#pragma unroll
                for (int j=0;j<8;++j){
                    unsigned short h = f2bu(vv[j]);
                    ah[j] = (short)h;
                    al[j] = (short)f2bu(vv[j] - __uint_as_float(((unsigned)h)<<16));
                }
#pragma unroll
                for (int ct=0; ct<2; ++ct){
                    acc[rt][ct] = __builtin_amdgcn_mfma_f32_16x16x32_bf16(ah, B1h[ct][kc], acc[rt][ct], 0,0,0);
                    acc[rt][ct] = __builtin_amdgcn_mfma_f32_16x16x32_bf16(ah, B1l[ct][kc], acc[rt][ct], 0,0,0);
                    acc[rt][ct] = __builtin_amdgcn_mfma_f32_16x16x32_bf16(al, B1h[ct][kc], acc[rt][ct], 0,0,0);
                }
            }
        }
        __syncthreads();   // Ef reads done before T1 writes race with nothing; keep order strict
#pragma unroll
        for (int ct=0; ct<2; ++ct){
            int col = cwb + ct*16 + n16;
            float bc = b1[col];
#pragma unroll
            for (int rt=0; rt<4; ++rt)
#pragma unroll
                for (int i=0;i<4;++i)
                    T1[rt*16 + quad*4 + i][col] = f2bu(silu_(acc[rt][ct][i] + bc));
        }
    }
    __syncthreads();

    // ---------- phases 0..2 (K=128, split-bf16 weights) ----------
    s8v Bh[2][4], Bl[2][4];
    for (int ph=0; ph<3; ++ph){
        const bf16* WH = (ph==0)? W2h : (ph==1)? Wmeh : Wv1h;
        const bf16* WL = (ph==0)? W2l : (ph==1)? Wmel : Wv1l;
        const unsigned short (*Tin)[136] = (ph==1)? (const unsigned short(*)[136])T2
                                                  : (const unsigned short(*)[136])T1;
#pragma unroll
        for (int ct=0; ct<2; ++ct){
            int nn = cwb + ct*16 + n16;
            const s8v* hp = (const s8v*)&WH[(size_t)nn*128];
            const s8v* lp = (const s8v*)&WL[(size_t)nn*128];
#pragma unroll
            for (int kc=0; kc<4; ++kc){
                Bh[ct][kc] = hp[kc*4 + quad];
                Bl[ct][kc] = lp[kc*4 + quad];
            }
        }
#pragma unroll
        for (int rt=0;rt<4;++rt)
#pragma unroll
            for (int ct=0;ct<2;++ct) acc[rt][ct] = (f4v){0.f,0.f,0.f,0.f};

#pragma unroll
        for (int kc=0; kc<4; ++kc){
#pragma unroll
            for (int rt=0; rt<4; ++rt){
                s8v a = *(const s8v*)&Tin[rt*16 + n16][kc*32 + quad*8];
#pragma unroll
                for (int ct=0; ct<2; ++ct){
                    acc[rt][ct] = __builtin_amdgcn_mfma_f32_16x16x32_bf16(a, Bh[ct][kc], acc[rt][ct], 0,0,0);
                    acc[rt][ct] = __builtin_amdgcn_mfma_f32_16x16x32_bf16(a, Bl[ct][kc], acc[rt][ct], 0,0,0);
                }
            }
        }
        if (ph==0){
#pragma unroll
            for (int ct=0; ct<2; ++ct){
                int col = cwb + ct*16 + n16;
                float bc = b2[col];
#pragma unroll
                for (int rt=0; rt<4; ++rt)
#pragma unroll
                    for (int i=0;i<4;++i)
                        T2[rt*16 + quad*4 + i][col] = f2bu(silu_(acc[rt][ct][i] + bc));
            }
            __syncthreads();
        } else if (ph==1){
            // T2 (the m-MLP input) fully consumed by the MFMA loop above.
            __syncthreads();
            // stage An rows (64 x 256B) coalesced into T2
#pragma unroll
            for (int it=0; it<4; ++it){
                int idx = tid + it*256;       // 0..1023
                int r = idx >> 4, c = idx & 15;
                *(s8v*)&T2[r][c*8] = *(const s8v*)&An[(size_t)seS[r]*HD + c*8];
            }
            __syncthreads();
            float anr[2][4][4];
#pragma unroll
            for (int ct=0; ct<2; ++ct){
                int col = cwb + ct*16 + n16;
#pragma unroll
                for (int rt=0; rt<4; ++rt)
#pragma unroll
                    for (int i=0;i<4;++i)
                        anr[ct][rt][i] = bf2f(*(const bf16*)&T2[rt*16 + quad*4 + i][col]);
            }
            __syncthreads();
            // stage Bn rows
#pragma unroll
            for (int it=0; it<4; ++it){
                int idx = tid + it*256;
                int r = idx >> 4, c = idx & 15;
                *(s8v*)&T2[r][c*8] = *(const s8v*)&Bn[(size_t)deS[r]*HD + c*8];
            }
            __syncthreads();
#pragma unroll
            for (int ct=0; ct<2; ++ct){
                int col = cwb + ct*16 + n16;
                float bc = bm[col];
#pragma unroll
                for (int rt=0; rt<4; ++rt)
#pragma unroll
                    for (int i=0;i<4;++i){
                        int row = rt*16 + quad*4 + i;
                        float v = silu_(acc[rt][ct][i] + bc
                                        + anr[ct][rt][i]
                                        + bf2f(*(const bf16*)&T2[row][col]));
                        T1[row][col] = f2bu(v);
                    }
            }
            __syncthreads();
            {
                int row = tid >> 2, seg = tid & 3;
                if (row0 + row < Ml){
                    const s8v* s = (const s8v*)&T1[row][seg*32];
                    s8v* d = (s8v*)&outM[(size_t)(row0+row)*HD + seg*32];
                    d[0]=s[0]; d[1]=s[1]; d[2]=s[2]; d[3]=s[3];
                }
            }
        } else {
#pragma unroll
            for (int ct=0; ct<2; ++ct){
                int col = cwb + ct*16 + n16;
                float bc = bv1[col];
#pragma unroll
                for (int rt=0; rt<4; ++rt)
#pragma unroll
                    for (int i=0;i<4;++i)
                        T2[rt*16 + quad*4 + i][col] = f2bu(acc[rt][ct][i] + bc);
            }
            __syncthreads();
            {
                int row = tid >> 2, seg = tid & 3;
                if (row0 + row < Ml){
                    const s8v* s = (const s8v*)&T2[row][seg*32];
                    s8v* d = (s8v*)&outG[(size_t)(row0+row)*HD + seg*32];
                    d[0]=s[0]; d[1]=s[1]; d[2]=s[2]; d[3]=s[3];
                }
            }
        }
    }
}

// ---------------- latency phase: per-node edge aggregation ----------------
__global__ __launch_bounds__(128)
void scatter_c(const int* __restrict__ rp, const int* __restrict__ srcp,
               const float* __restrict__ pos,
               const bf16* __restrict__ mB, const bf16* __restrict__ gB,
               const float* __restrict__ xvO,
               float* __restrict__ smC, float* __restrict__ mdC,
               float* __restrict__ avC, float* __restrict__ sdC, int n0, int n1)
{
    const int b = blockIdx.x;
    const int n = n0 + b;
    if (n >= n1) return;
    const int h = threadIdx.x;
    const int cbase = rp[n0];
    int p0 = rp[n], p1 = rp[n+1];
    float px0=pos[n*3],px1=pos[n*3+1],px2=pos[n*3+2];
    float sm=0,a0=0,a1=0,a2=0,m0=0,m1=0,m2=0,d0s=0,d1s=0,d2s=0;
    for (int p=p0;p<p1;++p){
        int ii=p-cbase; if ((unsigned)ii>=(unsigned)ECM) break;
        float mh=bf2f(mB[(size_t)ii*HD+h]);
        float gh=bf2f(gB[(size_t)ii*HD+h]);
        int sn=srcp[p]; sn=min(max(sn,0),NN-1);
        float d0=px0-pos[sn*3], d1=px1-pos[sn*3+1], d2=px2-pos[sn*3+2];
        sm+=mh;
        a0+=xvO[(size_t)sn*3*HD+h]*gh;
        a1+=xvO[(size_t)sn*3*HD+HD+h]*gh;
        a2+=xvO[(size_t)sn*3*HD+2*HD+h]*gh;
        m0+=mh*d0; m1+=mh*d1; m2+=mh*d2;
        d0s+=d0; d1s+=d1; d2s+=d2;
    }
    smC[(size_t)b*HD+h]=sm;
    mdC[(size_t)b*3*HD+h]=m0;
    mdC[(size_t)b*3*HD+HD+h]=m1;
    mdC[(size_t)b*3*HD+2*HD+h]=m2;
    avC[(size_t)b*3*HD+h]=a0;
    avC[(size_t)b*3*HD+HD+h]=a1;
    avC[(size_t)b*3*HD+2*HD+h]=a2;
    if (h==0){ sdC[b*3]=d0s; sdC[b*3+1]=d1s; sdC[b*3+2]=d2s; }
}

// ---------------- streaming epilogue: layernorm + equivariant update ----------------
__global__ __launch_bounds__(128)
void nu_lite(const float* __restrict__ gF, const float* __restrict__ swF,
             const float* __restrict__ xwF,
             const float* __restrict__ avC, const float* __restrict__ sdC,
             const float* __restrict__ xvO, float* __restrict__ xvN,
             float* __restrict__ xs,
             const float* __restrict__ bv2, const float* __restrict__ bs,
             const float* __restrict__ lng, const float* __restrict__ lnb,
             const float* __restrict__ vsg, int addRes, int n0, int n1)
{
    __shared__ float red[4];
    __shared__ float red2[2];
    const int b = blockIdx.x;
    const int n = n0 + b;
    if (n >= n1) return;
    const int h = threadIdx.x;
    const int w = h >> 6;
    const float xsv = xs[(size_t)n*HD+h];
    float xc = xwF[(size_t)b*HD+h] + swF[(size_t)b*HD+h] + bs[h];
    float s1=xc, s2=xc*xc;
#pragma unroll
    for (int off=1; off<64; off<<=1){ s1+=__shfl_xor(s1,off,64); s2+=__shfl_xor(s2,off,64); }
    if ((h&63)==0){ red[w*2]=s1; red[w*2+1]=s2; }
    __syncthreads();
    s1=red[0]+red[2]; s2=red[1]+red[3];
    float mu=s1*(1.f/128.f);
    float var=fmaxf(s2*(1.f/128.f)-mu*mu, 0.f);
    float xn=(xc-mu)*rsqrtf(var+1e-5f)*lng[h]+lnb[h];
    float ov0=xvO[(size_t)n*3*HD+h];
    float ov1=xvO[(size_t)n*3*HD+HD+h];
    float ov2=xvO[(size_t)n*3*HD+2*HD+h];
    float a0=avC[(size_t)b*3*HD+h];
    float a1=avC[(size_t)b*3*HD+HD+h];
    float a2=avC[(size_t)b*3*HD+2*HD+h];
    float d0s=sdC[b*3], d1s=sdC[b*3+1], d2s=sdC[b*3+2];
    float b2v=bv2[h];
    float v0=ov0+a0+gF[(size_t)(b*3+0)*HD+h]+b2v*d0s;
    float v1=ov1+a1+gF[(size_t)(b*3+1)*HD+h]+b2v*d1s;
    float v2=ov2+a2+gF[(size_t)(b*3+2)*HD+h]+b2v*d2s;
    float q=v0*v0+v1*v1+v2*v2;
#pragma unroll
    for (int off=1; off<64; off<<=1) q+=__shfl_xor(q,off,64);
    if ((h&63)==0) red2[w]=q;
    __syncthreads();
    q=fmaxf(red2[0]+red2[1], 0.f);
    float nrm=sqrtf(q*(1.f/128.f)+1e-5f);
    float scale=vsg[h]*sigm_(xn)/nrm;
    float r0=v0*scale, r1=v1*scale, r2=v2*scale;
    float nxs=silu_(xn);
    if (addRes){ nxs+=xsv; r0+=ov0; r1+=ov1; r2+=ov2; }
    xs[(size_t)n*HD+h]=nxs;
    xvN[(size_t)n*3*HD+h]=r0;
    xvN[(size_t)n*3*HD+HD+h]=r1;
    xvN[(size_t)n*3*HD+2*HD+h]=r2;
}

// ---------------- CSR build ----------------
__global__ void hist_kernel(const int* __restrict__ idx, int* __restrict__ cnt, int n, int nb){
    int i = blockIdx.x*256 + threadIdx.x;
    if (i < n){
        int v = idx[i]; v = min(max(v,0), nb-1);
        atomicAdd(&cnt[v], 1);
    }
}

// parallel 3-phase exclusive scan: block-local inclusive scan + block sums
__global__ __launch_bounds__(256)
void scan_blk(const int* __restrict__ cnt, int* __restrict__ rowptr,
              int* __restrict__ bsum, int n){
    const int b = blockIdx.x, t = threadIdx.x;
    const int i = b*256 + t;
    const int lane = t & 63, w = t >> 6;
    int v = (i < n) ? cnt[i] : 0;
    int s = v;
#pragma unroll
    for (int off=1; off<64; off<<=1){
        int u = __shfl_up(s, off, 64);
        if (lane >= off) s += u;
    }
    __shared__ int ws[4];
    if (lane == 63) ws[w] = s;
    __syncthreads();
    int add = 0;
#pragma unroll
    for (int j=0;j<4;++j) if (j < w) add += ws[j];
    s += add;
    if (i < n) rowptr[i+1] = s;          // inclusive scan -> exclusive via +1 shift
    if (t == 255) bsum[b] = s;           // padded lanes add 0, so this is the block total
    if (b == 0 && t == 0) rowptr[0] = 0;
}

// exclusive scan of block sums (nb <= 256)
__global__ __launch_bounds__(256)
void scan_bsum(int* __restrict__ bsum, int nb){
    const int t = threadIdx.x;
    const int lane = t & 63, w = t >> 6;
    int v = (t < nb) ? bsum[t] : 0;
    int s = v;
#pragma unroll
    for (int off=1; off<64; off<<=1){
        int u = __shfl_up(s, off, 64);
        if (lane >= off) s += u;
    }
    __shared__ int ws[4];
    if (lane == 63) ws[w] = s;
    __syncthreads();
    int add = 0;
#pragma unroll
    for (int j=0;j<4;++j) if (j < w) add += ws[j];
    s += add;
    if (t < nb) bsum[t] = s - v;         // exclusive
}

__global__ __launch_bounds__(256)
void scan_fix(int* __restrict__ rowptr, const int* __restrict__ bsum, int n){
    const int b = blockIdx.x, t = threadIdx.x;
    const int i = b*256 + t;
    const int off = bsum[b];
    if (i < n) rowptr[i+1] += off;       // i==n-1 covers rowptr[n]
}

__global__ void fill_kernel(const int* __restrict__ src, const int* __restrict__ dst,
                            const int* __restrict__ rowptr, int* __restrict__ cur,
                            int* __restrict__ elist, int* __restrict__ srcp,
                            int* __restrict__ dstp, int n){
    int e = blockIdx.x*256 + threadIdx.x;
    if (e < n){
        int d = dst[e]; d = min(max(d,0), NN-1);
        int slot = atomicAdd(&cur[d], 1);
        int p = rowptr[d] + slot;
        if (p >= 0 && p < NE){
            elist[p] = e;
            int s = src[e];
            srcp[p] = min(max(s,0), NN-1);
            dstp[p] = d;
        }
    }
}

__global__ void gptr_kernel(const int* __restrict__ batch, int* __restrict__ gptr){
    int n = blockIdx.x*256 + threadIdx.x;
    if (n >= NN) return;
    int b = batch[n]; b = min(max(b,0), NB-1);
    if (n == 0){
        for (int g=0; g<=b; ++g) gptr[g] = 0;
    } else {
        int bp = batch[n-1]; bp = min(max(bp,0), NB-1);
        for (int g=bp+1; g<=b; ++g) gptr[g] = n;
    }
    if (n == NN-1){
        for (int g=b+1; g<=NB; ++g) gptr[g] = NN;
    }
}

__global__ void xv_init(const float* __restrict__ xw, const float* __restrict__ pos,
                        float* __restrict__ xv){
    int n = blockIdx.x, h = threadIdx.x;
    float v = xw[(size_t)n*HD+h];
    xv[(size_t)n*3*HD + h]        = v*pos[n*3+0];
    xv[(size_t)n*3*HD + HD + h]   = v*pos[n*3+1];
    xv[(size_t)n*3*HD + 2*HD + h] = v*pos[n*3+2];
}

__global__ __launch_bounds__(128)
void capsule2(const float* __restrict__ Pf, const float* __restrict__ xv,
              const float* __restrict__ pvW, bf16* __restrict__ u){
    __shared__ float Pn[128];
    __shared__ float Xv[3][128];
    __shared__ float dots[48];
    __shared__ float pvn[16];
    __shared__ float capn2[8];
    int n = blockIdx.x, t = threadIdx.x;
    Pn[t] = Pf[(size_t)n*HD + t];
    Xv[0][t] = xv[(size_t)n*3*HD + t];
    Xv[1][t] = xv[(size_t)n*3*HD + HD + t];
    Xv[2][t] = xv[(size_t)n*3*HD + 2*HD + t];
    __syncthreads();
    if (t < 48){
        int pp = t/3, c = t%3;
        float a = 0.f;
        for (int hh=0; hh<128; ++hh) a += Xv[c][hh]*pvW[hh*16+pp];
        dots[t] = a;
    }
    if (t < 8){
        float a = 0.f;
        for (int d=0; d<16; ++d){ float x = Pn[t*16+d]; a += x*x; }
        capn2[t] = a;
    }
    __syncthreads();
    if (t < 16){
        float a = dots[t*3]*dots[t*3] + dots[t*3+1]*dots[t*3+1] + dots[t*3+2]*dots[t*3+2];
        pvn[t] = sqrtf(a + 1e-9f);
    }
    __syncthreads();
    int cap = t >> 4, d = t & 15;
    float n2 = capn2[cap];
    float pcv = Pn[t] * (n2/(1.f+n2)) * rsqrtf(n2 + 1e-9f);
    u[(size_t)n*HD + t] = __float2bfloat16(pcv + pvn[d]);
}

// two-stage pooling: slice WITHIN each graph's node range
__global__ void pool1(const int* __restrict__ gptr, const bf16* __restrict__ u,
                      float* __restrict__ Up){
    int blk = blockIdx.x;            // b*PSL + s
    int b = blk / PSL, s = blk % PSL;
    int h = threadIdx.x;
    int g0 = gptr[b], g1 = gptr[b+1];
    g0 = min(max(g0,0), NN); g1 = min(max(g1,0), NN);
    int len = g1 - g0;
    int lo = g0 + (int)(((long long)len * s) / PSL);
    int hi = g0 + (int)(((long long)len * (s+1)) / PSL);
    float a = 0.f;
    for (int n=lo; n<hi; ++n) a += bf2f(u[(size_t)n*HD + h]);
    Up[(size_t)blk*HD + h] = a;
}

__global__ void pool2(const float* __restrict__ Up, float* __restrict__ U){
    int b = blockIdx.x, h = threadIdx.x;
    float a = 0.f;
    for (int s=0; s<PSL; ++s) a += Up[(size_t)(b*PSL+s)*HD + h];
    U[b*HD + h] = a;
}

__global__ void graph_head(const float* __restrict__ U, const float* __restrict__ sW,
                           const float* __restrict__ aW, const float* __restrict__ ab,
                           const float* __restrict__ pW1, const float* __restrict__ pb1,
                           const float* __restrict__ pg1, const float* __restrict__ pbe1,
                           const float* __restrict__ pW2, const float* __restrict__ pb2,
                           const float* __restrict__ pg2, const float* __restrict__ pbe2,
                           const float* __restrict__ pW3, const float* __restrict__ pb3,
                           float* __restrict__ out){
    __shared__ float Ub[128];
    __shared__ float pooled[2048];
    __shared__ float vv[256];
    __shared__ float bbs[64], ccs[64];
    __shared__ float lg[8], aws[8];
    __shared__ float wcs[32];
    __shared__ float h1[64], h2[32];
    int b = blockIdx.x, t = threadIdx.x;
    if (t < 128) Ub[t] = U[b*HD + t];
    __syncthreads();
#pragma unroll
    for (int j=0;j<8;++j){
        int o = t + 256*j;
        int p = o >> 8, c = (o >> 5) & 7, e = o & 31;
        float a = 0.f;
#pragma unroll
        for (int d=0; d<16; ++d) a += Ub[p*16+d]*sW[((p*16+d)*8+c)*32+e];
        pooled[o] = a;
    }
    __syncthreads();
    {
        float s = 0.f;
        for (int p=0;p<8;++p) s += pooled[p*256 + t];
        s *= 0.125f;
        float n2 = s*s;
#pragma unroll
        for (int off=1; off<32; off<<=1) n2 += __shfl_xor(n2,off,32);
        vv[t] = s*(n2/(1.f+n2))*rsqrtf(n2+1e-9f);
    }
    __syncthreads();
    if (t < 64){
        int p = t>>3, c = t&7;
        float a = 0.f;
        for (int e=0;e<32;++e) a += pooled[p*256+c*32+e]*vv[c*32+e];
        bbs[t] = a;
    }
    __syncthreads();
    if (t < 64){
        int p = t>>3;
        float mx = -1e30f;
        for (int j=0;j<8;++j) mx = fmaxf(mx, bbs[p*8+j]);
        float sum = 0.f;
        for (int j=0;j<8;++j) sum += __expf(bbs[p*8+j]-mx);
        ccs[t] = __expf(bbs[t]-mx)/sum;
    }
    __syncthreads();
    {
        int c = t>>5;
        float s = 0.f;
        for (int p=0;p<8;++p) s += ccs[p*8+c]*pooled[p*256 + t];
        float n2 = s*s;
#pragma unroll
        for (int off=1; off<32; off<<=1) n2 += __shfl_xor(n2,off,32);
        vv[t] = s*(n2/(1.f+n2))*rsqrtf(n2+1e-9f);
    }
    __syncthreads();
    if (t < 8){
        float a = 0.f;
        for (int j=0;j<16;++j) a += vv[t*32+j]*aW[j];
        lg[t] = a + ab[0];
    }
    __syncthreads();
    if (t < 8){
        float mx = -1e30f;
        for (int j=0;j<8;++j) mx = fmaxf(mx, lg[j]);
        float sum = 0.f;
        for (int j=0;j<8;++j) sum += __expf(lg[j]-mx);
        aws[t] = __expf(lg[t]-mx)/sum;
    }
    __syncthreads();
    if (t < 32){
        float a = 0.f;
        for (int c=0;c<8;++c) a += aws[c]*vv[c*32+t];
        wcs[t] = a;
    }
    __syncthreads();
    if (t < 64){
        float a = 0.f;
        for (int e=0;e<32;++e) a += wcs[e]*pW1[e*64+t];
        h1[t] = silu_((a+pb1[t])*pg1[t]+pbe1[t]);
    }
    __syncthreads();
    if (t < 32){
        float a = 0.f;
        for (int j=0;j<64;++j) a += h1[j]*pW2[j*32+t];
        h2[t] = silu_((a+pb2[t])*pg2[t]+pbe2[t]);
    }
    __syncthreads();
    if (t == 0){
        float a = 0.f;
        for (int j=0;j<32;++j) a += h2[j]*pW3[j];
        a += pb3[0];
        if (!finite_(a)) a = 999.f;
        out[b] = a;
    }
}

__global__ void sentinel_k(float* __restrict__ out, float v){
    out[threadIdx.x] = v;
}

// ---------------- host side ----------------
extern "C" void kernel_launch(void* const* d_in, const int* in_sizes, int n_in,
                              void* d_out, int out_size, void* d_ws, size_t ws_size,
                              hipStream_t stream)
{
    (void)in_sizes; (void)n_in; (void)out_size;
    const float* x    = (const float*)d_in[0];
    const float* eat  = (const float*)d_in[1];
    const float* pos  = (const float*)d_in[2];
    const int*  eidx  = (const int*)d_in[3];
    const int*  batch = (const int*)d_in[4];
    const float* neW1=(const float*)d_in[5],  *neb1=(const float*)d_in[6],
               * neg1=(const float*)d_in[7],  *nebe1=(const float*)d_in[8];
    const float* neW2=(const float*)d_in[9],  *neb2=(const float*)d_in[10],
               * neg2=(const float*)d_in[11], *nebe2=(const float*)d_in[12];
    const float* eeW1=(const float*)d_in[13], *eeb1=(const float*)d_in[14];
    const float* eeW2=(const float*)d_in[15], *eeb2=(const float*)d_in[16];
    const float* ivW =(const float*)d_in[17], *ivb =(const float*)d_in[18];
    const float* cWma=(const float*)d_in[19], *cWmb=(const float*)d_in[20],
               * cWme=(const float*)d_in[21], *cbm =(const float*)d_in[22];
    const float* cWsx=(const float*)d_in[23], *cWsa=(const float*)d_in[24],
               * cbs =(const float*)d_in[25];
    const float* cWv1=(const float*)d_in[26], *cbv1=(const float*)d_in[27],
               * cWv2=(const float*)d_in[28], *cbv2=(const float*)d_in[29];
    const float* lng =(const float*)d_in[30], *lnb =(const float*)d_in[31],
               * vsg =(const float*)d_in[32];
    const float* pcW =(const float*)d_in[33], *pcb =(const float*)d_in[34];
    const float* pvW =(const float*)d_in[35];
    const float* sW  =(const float*)d_in[36];
    const float* aW  =(const float*)d_in[37], *ab  =(const float*)d_in[38];
    const float* pW1 =(const float*)d_in[39], *pb1 =(const float*)d_in[40],
               * pg1 =(const float*)d_in[41], *pbe1=(const float*)d_in[42];
    const float* pW2 =(const float*)d_in[43], *pb2 =(const float*)d_in[44],
               * pg2 =(const float*)d_in[45], *pbe2=(const float*)d_in[46];
    const float* pW3 =(const float*)d_in[47], *pb3 =(const float*)d_in[48];

    const int* src = eidx;
    const int* dst = eidx + NE;

    char* wp = (char*)d_ws;
    auto alloc = [&](size_t bytes)->char*{
        char* p = wp;
        wp += (bytes + 255) & ~(size_t)255;
        return p;
    };
    bf16*  bufM  = (bf16*) alloc((size_t)ECM*HD*2);
    bf16*  bufG  = (bf16*) alloc((size_t)ECM*HD*2);
    float* xs    = (float*)alloc((size_t)NN*HD*4);
    float* xvA   = (float*)alloc((size_t)NN*3*HD*4);
    float* xvB   = (float*)alloc((size_t)NN*3*HD*4);
    bf16*  An    = (bf16*) alloc((size_t)NN*HD*2);
    bf16*  Bn    = (bf16*) alloc((size_t)NN*HD*2);
    float* smC   = (float*)alloc((size_t)CN*HD*4);
    float* mdC   = (float*)alloc((size_t)CN*3*HD*4);
    float* avC   = (float*)alloc((size_t)CN*3*HD*4);
    float* sdC   = (float*)alloc((size_t)CN*3*4);
    bf16*  WtH   = (bf16*) alloc((size_t)7*HD*HD*2);
    bf16*  WtL   = (bf16*) alloc((size_t)7*HD*HD*2);
    bf16*  W1h   = (bf16*) alloc((size_t)HD*64*2);
    bf16*  W1l   = (bf16*) alloc((size_t)HD*64*2);
    float* Up    = (float*)alloc((size_t)NB*PSL*HD*4);
    float* Ubuf  = (float*)alloc((size_t)NB*HD*4);
    int* rowptr  = (int*)alloc((size_t)(NN+1)*4);
    int* cnt     = (int*)alloc((size_t)NN*4);
    int* bsum    = (int*)alloc((size_t)256*4);
    int* elist   = (int*)alloc((size_t)NE*4);
    int* srcp    = (int*)alloc((size_t)NE*4);
    int* dstp    = (int*)alloc((size_t)NE*4);
    int* gptr    = (int*)alloc((size_t)(NB+1)*4);
    size_t used  = (size_t)(wp - (char*)d_ws);   // ~249 MiB

    if (used > ws_size){
        sentinel_k<<<1, NB, 0, stream>>>((float*)d_out, -1.f - (float)(ws_size >> 20));
        return;
    }
    float* tmpF = xvB;
    bf16*  ubuf = An;
    float* Pf   = xvA;
    // nu-stage GEMM outputs overlay bufM/bufG (dead between scatter_c(c) and edge_pipe(c+1)):
    float* gF  = (float*)bufM;
    float* swF = gF  + (size_t)3*CN*HD;
    float* xwF = swF + (size_t)CN*HD;

    // ---- CSR + gptr + weight splits ----
    hipMemsetAsync(cnt, 0, (size_t)NN*4, stream);
    hist_kernel<<<(NE+255)/256, 256, 0, stream>>>(dst, cnt, NE, NN);
    const int SBLK = (NN+255)/256;   // 196 blocks
    scan_blk<<<SBLK, 256, 0, stream>>>(cnt, rowptr, bsum, NN);
    scan_bsum<<<1, 256, 0, stream>>>(bsum, SBLK);
    scan_fix<<<SBLK, 256, 0, stream>>>(rowptr, bsum, NN);
    hipMemsetAsync(cnt, 0, (size_t)NN*4, stream);
    fill_kernel<<<(NE+255)/256, 256, 0, stream>>>(src, dst, rowptr, cnt, elist, srcp, dstp, NE);
    gptr_kernel<<<(NN+255)/256, 256, 0, stream>>>(batch, gptr);
    wprep1<<<32,256,0,stream>>>(eeW1, W1h, W1l);
    wprep<<<64,256,0,stream>>>(eeW2, WtH, WtL);
    for (int l=0;l<3;++l){
        wprep<<<64,256,0,stream>>>(cWme + (size_t)l*HD*HD, WtH + (size_t)(1+l)*HD*HD,
                                   WtL + (size_t)(1+l)*HD*HD);
        wprep<<<64,256,0,stream>>>(cWv1 + (size_t)l*HD*HD, WtH + (size_t)(4+l)*HD*HD,
                                   WtL + (size_t)(4+l)*HD*HD);
    }

    const int GN = (NN+63)/64;
    const int GE = ECM/64;
    const int G3 = ((3*CN+63)/64) + 2*((CN+63)/64);

    // ---- node embeddings ----
    gemmk<M_BNSILU><<<GN,256,0,stream>>>(x, neW1, neb1, neg1, nebe1, tmpF, 0, NN, 92);
    gemmk<M_BNSILU><<<GN,256,0,stream>>>(tmpF, neW2, neb2, neg2, nebe2, xs, 0, NN, 128);
    gemmk<M_BIAS><<<GN,256,0,stream>>>(xs, ivW, ivb, nullptr, nullptr, tmpF, 0, NN, 128);
    xv_init<<<NN, 128, 0, stream>>>(tmpF, pos, xvA);

    // ---- message-passing layers ----
    float* xvO = xvA;
    float* xvN = xvB;
    for (int l=0; l<3; ++l){
        const float* Wma = cWma + (size_t)l*HD*HD;
        const float* Wmb = cWmb + (size_t)l*HD*HD;
        const float* bm  = cbm  + (size_t)l*HD;
        const float* Wsx = cWsx + (size_t)l*HD*HD;
        const float* Wsa = cWsa + (size_t)l*HD*HD;
        const float* bs  = cbs  + (size_t)l*HD;
        const float* bv1 = cbv1 + (size_t)l*HD;
        const float* Wv2 = cWv2 + (size_t)l*HD*HD;
        const float* bv2 = cbv2 + (size_t)l*HD;
        const bf16* Wmeh = WtH + (size_t)(1+l)*HD*HD;
        const bf16* Wmel = WtL + (size_t)(1+l)*HD*HD;
        const bf16* Wv1h = WtH + (size_t)(4+l)*HD*HD;
        const bf16* Wv1l = WtL + (size_t)(4+l)*HD*HD;

        gemmk<M_PLAIN><<<GN,256,0,stream>>>(xs, Wma, nullptr, nullptr, nullptr, An, 1, NN, 128);
        gemmk<M_PLAIN><<<GN,256,0,stream>>>(xs, Wmb, nullptr, nullptr, nullptr, Bn, 1, NN, 128);

        for (int c=0; c<NCH; ++c){
            int n0 = c*CN, n1 = n0+CN;
            edge_pipe<<<GE,256,0,stream>>>(eat, elist, srcp, dstp,
                                           W1h, W1l, eeb1,
                                           WtH, WtL, eeb2,
                                           Wmeh, Wmel, bm,
                                           An, Bn,
                                           Wv1h, Wv1l, bv1,
                                           rowptr, n0, n1, bufM, bufG);
            scatter_c<<<CN,128,0,stream>>>(rowptr, srcp, pos, bufM, bufG, xvO,
                                           smC, mdC, avC, sdC, n0, n1);
            gemm3<<<G3,256,0,stream>>>(mdC, Wv2, gF, 3*CN,
                                       smC, Wsa, swF, CN,
                                       xs + (size_t)n0*HD, Wsx, xwF, CN);
            nu_lite<<<CN,128,0,stream>>>(gF, swF, xwF, avC, sdC,
                                         xvO, xvN, xs,
                                         bv2, bs,
                                         lng + (size_t)l*HD, lnb + (size_t)l*HD,
                                         vsg + (size_t)l*HD, l>0 ? 1 : 0, n0, n1);
        }
        float* t = xvO; xvO = xvN; xvN = t;
    }

    // ---- capsules & head ----
    gemmk<M_BIAS><<<GN,256,0,stream>>>(xs, pcW, pcb, nullptr, nullptr, Pf, 0, NN, 128);
    capsule2<<<NN, 128, 0, stream>>>(Pf, xvO, pvW, ubuf);
    pool1<<<NB*PSL, 128, 0, stream>>>(gptr, ubuf, Up);
    pool2<<<NB, 128, 0, stream>>>(Up, Ubuf);
    graph_head<<<NB, 256, 0, stream>>>(Ubuf, sW, aW, ab,
                                       pW1, pb1, pg1, pbe1,
                                       pW2, pb2, pg2, pbe2,
                                       pW3, pb3, (float*)d_out);
}

// Round 5
// 3333.282 us; speedup vs baseline: 1.0429x; 1.0429x over previous
//
#include <hip/hip_runtime.h>
#include <hip/hip_bf16.h>
#include <math.h>

#define NN 50000
#define NE 400000
#define HD 128
#define NB 64
#define NCH 8
#define CN 6250          // nodes per chunk
#define ECM 53248        // max edges per chunk
#define PSL 16           // pool slices

typedef __hip_bfloat16 bf16;
typedef __attribute__((ext_vector_type(4))) unsigned short us4;
typedef __attribute__((ext_vector_type(8))) short s8v;    // 8 bf16 MFMA frag
typedef __attribute__((ext_vector_type(4))) float f4v;    // MFMA accumulator

__device__ __forceinline__ float sigm_(float x){ return 1.f/(1.f+__expf(-x)); }
__device__ __forceinline__ float silu_(float x){ return x*sigm_(x); }
__device__ __forceinline__ float bf2f(bf16 x){ return __bfloat162float(x); }
__device__ __forceinline__ unsigned short f2bu(float f){
    bf16 h = __float2bfloat16(f);
    return *reinterpret_cast<unsigned short*>(&h);
}
__device__ __forceinline__ bool finite_(float v){ return fabsf(v) <= 1e37f; }

enum { M_PLAIN=0, M_BIAS, M_BNSILU };

// ---------------- split-transpose weight prep ----------------
__global__ void wprep(const float* __restrict__ W, bf16* __restrict__ H, bf16* __restrict__ L){
    int i = blockIdx.x*256 + threadIdx.x;
    int k = i >> 7, n = i & 127;
    float w = W[i];
    bf16 h = __float2bfloat16(w);
    float r = w - bf2f(h);
    H[n*128 + k] = h;
    L[n*128 + k] = __float2bfloat16(r);
}

__global__ void wprep1(const float* __restrict__ W, bf16* __restrict__ H, bf16* __restrict__ L){
    int i = blockIdx.x*256 + threadIdx.x;
    int n = i >> 6, k = i & 63;
    float w = (k < 41) ? W[(size_t)k*HD + n] : 0.f;
    bf16 h = __float2bfloat16(w);
    float r = w - bf2f(h);
    H[n*64 + k] = h;
    L[n*64 + k] = __float2bfloat16(r);
}

// ---------------- generic tiled GEMM ----------------
template<int MODE>
__global__ __launch_bounds__(256)
void gemmk(const float* __restrict__ A, const float* __restrict__ W,
           const float* __restrict__ bias, const float* __restrict__ gg,
           const float* __restrict__ be, void* __restrict__ Cv, int owf, int M, int K)
{
    const int row0 = blockIdx.x * 64;
    if (row0 >= M) return;
    __shared__ float As[32][68];
    __shared__ float Ws[32][128];
    const int tid = threadIdx.x;
    const int tx = tid & 15, ty = tid >> 4;
    const int col0 = tx*8;
    float acc[4][8];
#pragma unroll
    for (int r=0;r<4;++r)
#pragma unroll
        for (int j=0;j<8;++j) acc[r][j]=0.f;
    const int mload = tid >> 2;
    const int kload = (tid & 3) << 3;
    const int grow = row0 + mload;
    const bool rv = grow < M;

    for (int k0 = 0; k0 < K; k0 += 32) {
        if (rv && ((K & 3) == 0) && (k0 + kload + 8 <= K)) {
            const float* ap = A + (size_t)grow*K + k0 + kload;
            float4 v0 = *(const float4*)ap;
            float4 v1 = *(const float4*)(ap+4);
            As[kload+0][mload]=v0.x; As[kload+1][mload]=v0.y;
            As[kload+2][mload]=v0.z; As[kload+3][mload]=v0.w;
            As[kload+4][mload]=v1.x; As[kload+5][mload]=v1.y;
            As[kload+6][mload]=v1.z; As[kload+7][mload]=v1.w;
        } else {
#pragma unroll
            for (int j=0;j<8;++j){
                int kg = k0 + kload + j;
                As[kload+j][mload] = (rv && kg<K) ? A[(size_t)grow*K+kg] : 0.f;
            }
        }
        if (k0 + 32 <= K) {
#pragma unroll
            for (int j=0;j<4;++j){
                int el = (tid + j*256)*4;
                int kk = el >> 7, col = el & 127;
                *(float4*)&Ws[kk][col] = *(const float4*)&W[(size_t)(k0+kk)*HD + col];
            }
        } else {
#pragma unroll
            for (int j=0;j<16;++j){
                int el = tid*16 + j;
                int kk = el >> 7, col = el & 127;
                int kg = k0 + kk;
                Ws[kk][col] = (kg < K) ? W[(size_t)kg*HD + col] : 0.f;
            }
        }
        __syncthreads();
#pragma unroll
        for (int k=0;k<32;++k){
            float4 a4 = *(const float4*)&As[k][ty*4];
            float4 w0 = *(const float4*)&Ws[k][col0];
            float4 w1 = *(const float4*)&Ws[k][col0+4];
            float av[4] = {a4.x,a4.y,a4.z,a4.w};
            float wv[8] = {w0.x,w0.y,w0.z,w0.w,w1.x,w1.y,w1.z,w1.w};
#pragma unroll
            for (int r=0;r<4;++r)
#pragma unroll
                for (int j=0;j<8;++j) acc[r][j] += av[r]*wv[j];
        }
        __syncthreads();
    }
#pragma unroll
    for (int r=0;r<4;++r){
        int orow = row0 + ty*4 + r;
        if (orow >= M) continue;
        float o[8];
#pragma unroll
        for (int j=0;j<8;++j) o[j]=acc[r][j];
        if constexpr (MODE==M_BIAS || MODE==M_BNSILU){
#pragma unroll
            for (int j=0;j<8;++j) o[j] += bias[col0+j];
        }
        if constexpr (MODE==M_BNSILU){
#pragma unroll
            for (int j=0;j<8;++j) o[j] = silu_(o[j]*gg[col0+j] + be[col0+j]);
        }
        if (owf){
            bf16* C = (bf16*)Cv;
#pragma unroll
            for (int j=0;j<8;++j) C[(size_t)orow*HD+col0+j] = __float2bfloat16(o[j]);
        } else {
            float* C = (float*)Cv;
            float4* cp = (float4*)&C[(size_t)orow*HD + col0];
            cp[0] = make_float4(o[0],o[1],o[2],o[3]);
            cp[1] = make_float4(o[4],o[5],o[6],o[7]);
        }
    }
}

// ---------------- fused 3-GEMM (K=128, f32, no bias) for the nu stage ----------------
__global__ __launch_bounds__(256)
void gemm3(const float* __restrict__ A0, const float* __restrict__ W0, float* __restrict__ C0, int M0,
           const float* __restrict__ A1, const float* __restrict__ W1, float* __restrict__ C1, int M1,
           const float* __restrict__ A2, const float* __restrict__ W2, float* __restrict__ C2, int M2)
{
    const int nb0 = (M0+63)>>6, nb1 = (M1+63)>>6;
    int bb = (int)blockIdx.x;
    const float *A, *W; float* C; int M;
    if (bb < nb0){ A=A0; W=W0; C=C0; M=M0; }
    else if (bb < nb0+nb1){ bb -= nb0; A=A1; W=W1; C=C1; M=M1; }
    else { bb -= nb0+nb1; A=A2; W=W2; C=C2; M=M2; }
    const int row0 = bb*64;

    __shared__ float As[32][68];
    __shared__ float Ws[32][128];
    const int tid = threadIdx.x;
    const int tx = tid & 15, ty = tid >> 4;
    const int col0 = tx*8;
    float acc[4][8];
#pragma unroll
    for (int r=0;r<4;++r)
#pragma unroll
        for (int j=0;j<8;++j) acc[r][j]=0.f;
    const int mload = tid >> 2;
    const int kload = (tid & 3) << 3;
    const int grow = row0 + mload;
    const bool rv = grow < M;

    for (int k0 = 0; k0 < 128; k0 += 32) {
        if (rv) {
            const float* ap = A + (size_t)grow*128 + k0 + kload;
            float4 v0 = *(const float4*)ap;
            float4 v1 = *(const float4*)(ap+4);
            As[kload+0][mload]=v0.x; As[kload+1][mload]=v0.y;
            As[kload+2][mload]=v0.z; As[kload+3][mload]=v0.w;
            As[kload+4][mload]=v1.x; As[kload+5][mload]=v1.y;
            As[kload+6][mload]=v1.z; As[kload+7][mload]=v1.w;
        } else {
#pragma unroll
            for (int j=0;j<8;++j) As[kload+j][mload] = 0.f;
        }
#pragma unroll
        for (int j=0;j<4;++j){
            int el = (tid + j*256)*4;
            int kk = el >> 7, col = el & 127;
            *(float4*)&Ws[kk][col] = *(const float4*)&W[(size_t)(k0+kk)*HD + col];
        }
        __syncthreads();
#pragma unroll
        for (int k=0;k<32;++k){
            float4 a4 = *(const float4*)&As[k][ty*4];
            float4 w0 = *(const float4*)&Ws[k][col0];
            float4 w1 = *(const float4*)&Ws[k][col0+4];
            float av[4] = {a4.x,a4.y,a4.z,a4.w};
            float wv[8] = {w0.x,w0.y,w0.z,w0.w,w1.x,w1.y,w1.z,w1.w};
#pragma unroll
            for (int r=0;r<4;++r)
#pragma unroll
                for (int j=0;j<8;++j) acc[r][j] += av[r]*wv[j];
        }
        __syncthreads();
    }
#pragma unroll
    for (int r=0;r<4;++r){
        int orow = row0 + ty*4 + r;
        if (orow >= M) continue;
        float4* cp = (float4*)&C[(size_t)orow*HD + col0];
        cp[0] = make_float4(acc[r][0],acc[r][1],acc[r][2],acc[r][3]);
        cp[1] = make_float4(acc[r][4],acc[r][5],acc[r][6],acc[r][7]);
    }
}

// ---------------- MFMA fused edge pipeline ----------------
// round-3 structure; phase 1 An/Bn gathers replaced by register-prefetch
// (issued before the phase-1 MFMA loop, latency hidden under MFMA) + LDS
// transpose roundtrip through the dead T1/T2 windows.
__global__ __launch_bounds__(256)
void edge_pipe(const float* __restrict__ eat,
               const int* __restrict__ elist, const int* __restrict__ srcp,
               const int* __restrict__ dstp,
               const bf16* __restrict__ W1h, const bf16* __restrict__ W1l,
               const float* __restrict__ b1,
               const bf16* __restrict__ W2h, const bf16* __restrict__ W2l,
               const float* __restrict__ b2,
               const bf16* __restrict__ Wmeh, const bf16* __restrict__ Wmel,
               const float* __restrict__ bm,
               const bf16* __restrict__ An, const bf16* __restrict__ Bn,
               const bf16* __restrict__ Wv1h, const bf16* __restrict__ Wv1l,
               const float* __restrict__ bv1,
               const int* __restrict__ rp, int rn0, int rn1,
               bf16* __restrict__ outM, bf16* __restrict__ outG)
{
    __shared__ __align__(16) unsigned short T1[64][136];
    __shared__ __align__(16) unsigned short T2[64][136];
    __shared__ int elS[64], seS[64], deS[64];

    const int cbase = rp[rn0];
    const int Ml = min(ECM, max(rp[rn1]-cbase, 0));
    const int row0 = blockIdx.x*64;
    if (row0 >= Ml) return;
    const int tid = threadIdx.x;
    const int lane = tid & 63, wave = tid >> 6;
    const int quad = lane >> 4, n16 = lane & 15;
    const int cwb = wave*32;

    if (tid < 64){
        int r = row0 + tid;
        bool v = r < Ml;
        int p = cbase + (v ? r : 0);
        elS[tid] = v ? min(max(elist[p],0),NE-1) : 0;
        seS[tid] = v ? srcp[p] : 0;
        deS[tid] = v ? dstp[p] : 0;
    }
    __syncthreads();

    f4v acc[4][2];

    // ---------- G1: K=64(padded) split MFMA ----------
    {
        s8v B1h[2][2], B1l[2][2];
#pragma unroll
        for (int ct=0; ct<2; ++ct){
            int nn = cwb + ct*16 + n16;
#pragma unroll
            for (int kc=0; kc<2; ++kc){
                B1h[ct][kc] = *(const s8v*)&W1h[(size_t)nn*64 + kc*32 + quad*8];
                B1l[ct][kc] = *(const s8v*)&W1l[(size_t)nn*64 + kc*32 + quad*8];
            }
        }
#pragma unroll
        for (int rt=0;rt<4;++rt)
#pragma unroll
            for (int ct=0;ct<2;++ct) acc[rt][ct] = (f4v){0.f,0.f,0.f,0.f};

#pragma unroll
        for (int rt=0; rt<4; ++rt){
            int arow = elS[rt*16 + n16];
#pragma unroll
            for (int kc=0; kc<2; ++kc){
                s8v ah, al;
#pragma unroll
                for (int j=0;j<8;++j){
                    int k = kc*32 + quad*8 + j;
                    float v = (k < 41) ? eat[(size_t)arow*41 + k] : 0.f;
                    unsigned short h = f2bu(v);
                    ah[j] = (short)h;
                    al[j] = (short)f2bu(v - __uint_as_float(((unsigned)h)<<16));
                }
#pragma unroll
                for (int ct=0; ct<2; ++ct){
                    acc[rt][ct] = __builtin_amdgcn_mfma_f32_16x16x32_bf16(ah, B1h[ct][kc], acc[rt][ct], 0,0,0);
                    acc[rt][ct] = __builtin_amdgcn_mfma_f32_16x16x32_bf16(ah, B1l[ct][kc], acc[rt][ct], 0,0,0);
                    acc[rt][ct] = __builtin_amdgcn_mfma_f32_16x16x32_bf16(al, B1h[ct][kc], acc[rt][ct], 0,0,0);
                }
            }
        }
#pragma unroll
        for (int ct=0; ct<2; ++ct){
            int col = cwb + ct*16 + n16;
            float bc = b1[col];
#pragma unroll
            for (int rt=0; rt<4; ++rt)
#pragma unroll
                for (int i=0;i<4;++i)
                    T1[rt*16 + quad*4 + i][col] = f2bu(silu_(acc[rt][ct][i] + bc));
        }
    }
    __syncthreads();

    // ---------- phases 0..2 (K=128, split-bf16 weights) ----------
    s8v Bh[2][4], Bl[2][4];
    for (int ph=0; ph<3; ++ph){
        const bf16* WH = (ph==0)? W2h : (ph==1)? Wmeh : Wv1h;
        const bf16* WL = (ph==0)? W2l : (ph==1)? Wmel : Wv1l;
        const unsigned short (*Tin)[136] = (ph==1)? (const unsigned short(*)[136])T2
                                                  : (const unsigned short(*)[136])T1;
#pragma unroll
        for (int ct=0; ct<2; ++ct){
            int nn = cwb + ct*16 + n16;
            const s8v* hp = (const s8v*)&WH[(size_t)nn*128];
            const s8v* lp = (const s8v*)&WL[(size_t)nn*128];
#pragma unroll
            for (int kc=0; kc<4; ++kc){
                Bh[ct][kc] = hp[kc*4 + quad];
                Bl[ct][kc] = lp[kc*4 + quad];
            }
        }
#pragma unroll
        for (int rt=0;rt<4;++rt)
#pragma unroll
            for (int ct=0;ct<2;++ct) acc[rt][ct] = (f4v){0.f,0.f,0.f,0.f};

        // phase-1 prefetch: coalesced An/Bn rows into registers; latency is
        // hidden under the 64-MFMA loop below (no drain before first use).
        s8v anR[4], bnR[4];
        if (ph==1){
#pragma unroll
            for (int it=0; it<4; ++it){
                int idx = tid + it*256;       // 0..1023
                int r = idx >> 4, c = idx & 15;
                anR[it] = *(const s8v*)&An[(size_t)seS[r]*HD + c*8];
                bnR[it] = *(const s8v*)&Bn[(size_t)deS[r]*HD + c*8];
            }
        }

#pragma unroll
        for (int kc=0; kc<4; ++kc){
#pragma unroll
            for (int rt=0; rt<4; ++rt){
                s8v a = *(const s8v*)&Tin[rt*16 + n16][kc*32 + quad*8];
#pragma unroll
                for (int ct=0; ct<2; ++ct){
                    acc[rt][ct] = __builtin_amdgcn_mfma_f32_16x16x32_bf16(a, Bh[ct][kc], acc[rt][ct], 0,0,0);
                    acc[rt][ct] = __builtin_amdgcn_mfma_f32_16x16x32_bf16(a, Bl[ct][kc], acc[rt][ct], 0,0,0);
                }
            }
        }
        if (ph==0){
#pragma unroll
            for (int ct=0; ct<2; ++ct){
                int col = cwb + ct*16 + n16;
                float bc = b2[col];
#pragma unroll
                for (int rt=0; rt<4; ++rt)
#pragma unroll
                    for (int i=0;i<4;++i)
                        T2[rt*16 + quad*4 + i][col] = f2bu(silu_(acc[rt][ct][i] + bc));
            }
            __syncthreads();
        } else if (ph==1){
            __syncthreads();   // all waves done reading T2 (MFMA); T1 dead since phase-0 end
            // transpose-roundtrip the prefetched rows: An -> T1, Bn -> T2
#pragma unroll
            for (int it=0; it<4; ++it){
                int idx = tid + it*256;
                int r = idx >> 4, c = idx & 15;
                *(s8v*)&T1[r][c*8] = anR[it];
                *(s8v*)&T2[r][c*8] = bnR[it];
            }
            __syncthreads();
            // epilogue: each (row,col) slot is owned by exactly one thread, so
            // reading its An value from T1[row][col] and overwriting the same
            // slot with the output needs no extra barrier.
#pragma unroll
            for (int ct=0; ct<2; ++ct){
                int col = cwb + ct*16 + n16;
                float bc = bm[col];
#pragma unroll
                for (int rt=0; rt<4; ++rt)
#pragma unroll
                    for (int i=0;i<4;++i){
                        int row = rt*16 + quad*4 + i;
                        float v = silu_(acc[rt][ct][i] + bc
                                        + bf2f(*(const bf16*)&T1[row][col])
                                        + bf2f(*(const bf16*)&T2[row][col]));
                        T1[row][col] = f2bu(v);
                    }
            }
            __syncthreads();
            {
                int row = tid >> 2, seg = tid & 3;
                if (row0 + row < Ml){
                    const s8v* s = (const s8v*)&T1[row][seg*32];
                    s8v* d = (s8v*)&outM[(size_t)(row0+row)*HD + seg*32];
                    d[0]=s[0]; d[1]=s[1]; d[2]=s[2]; d[3]=s[3];
                }
            }
        } else {
#pragma unroll
            for (int ct=0; ct<2; ++ct){
                int col = cwb + ct*16 + n16;
                float bc = bv1[col];
#pragma unroll
                for (int rt=0; rt<4; ++rt)
#pragma unroll
                    for (int i=0;i<4;++i)
                        T2[rt*16 + quad*4 + i][col] = f2bu(acc[rt][ct][i] + bc);
            }
            __syncthreads();
            {
                int row = tid >> 2, seg = tid & 3;
                if (row0 + row < Ml){
                    const s8v* s = (const s8v*)&T2[row][seg*32];
                    s8v* d = (s8v*)&outG[(size_t)(row0+row)*HD + seg*32];
                    d[0]=s[0]; d[1]=s[1]; d[2]=s[2]; d[3]=s[3];
                }
            }
        }
    }
}

// ---------------- latency phase: per-node edge aggregation ----------------
__global__ __launch_bounds__(128)
void scatter_c(const int* __restrict__ rp, const int* __restrict__ srcp,
               const float* __restrict__ pos,
               const bf16* __restrict__ mB, const bf16* __restrict__ gB,
               const float* __restrict__ xvO,
               float* __restrict__ smC, float* __restrict__ mdC,
               float* __restrict__ avC, float* __restrict__ sdC, int n0, int n1)
{
    const int b = blockIdx.x;
    const int n = n0 + b;
    if (n >= n1) return;
    const int h = threadIdx.x;
    const int cbase = rp[n0];
    int p0 = rp[n], p1 = rp[n+1];
    float px0=pos[n*3],px1=pos[n*3+1],px2=pos[n*3+2];
    float sm=0,a0=0,a1=0,a2=0,m0=0,m1=0,m2=0,d0s=0,d1s=0,d2s=0;
    for (int p=p0;p<p1;++p){
        int ii=p-cbase; if ((unsigned)ii>=(unsigned)ECM) break;
        float mh=bf2f(mB[(size_t)ii*HD+h]);
        float gh=bf2f(gB[(size_t)ii*HD+h]);
        int sn=srcp[p]; sn=min(max(sn,0),NN-1);
        float d0=px0-pos[sn*3], d1=px1-pos[sn*3+1], d2=px2-pos[sn*3+2];
        sm+=mh;
        a0+=xvO[(size_t)sn*3*HD+h]*gh;
        a1+=xvO[(size_t)sn*3*HD+HD+h]*gh;
        a2+=xvO[(size_t)sn*3*HD+2*HD+h]*gh;
        m0+=mh*d0; m1+=mh*d1; m2+=mh*d2;
        d0s+=d0; d1s+=d1; d2s+=d2;
    }
    smC[(size_t)b*HD+h]=sm;
    mdC[(size_t)b*3*HD+h]=m0;
    mdC[(size_t)b*3*HD+HD+h]=m1;
    mdC[(size_t)b*3*HD+2*HD+h]=m2;
    avC[(size_t)b*3*HD+h]=a0;
    avC[(size_t)b*3*HD+HD+h]=a1;
    avC[(size_t)b*3*HD+2*HD+h]=a2;
    if (h==0){ sdC[b*3]=d0s; sdC[b*3+1]=d1s; sdC[b*3+2]=d2s; }
}

// ---------------- streaming epilogue: layernorm + equivariant update ----------------
__global__ __launch_bounds__(128)
void nu_lite(const float* __restrict__ gF, const float* __restrict__ swF,
             const float* __restrict__ xwF,
             const float* __restrict__ avC, const float* __restrict__ sdC,
             const float* __restrict__ xvO, float* __restrict__ xvN,
             float* __restrict__ xs,
             const float* __restrict__ bv2, const float* __restrict__ bs,
             const float* __restrict__ lng, const float* __restrict__ lnb,
             const float* __restrict__ vsg, int addRes, int n0, int n1)
{
    __shared__ float red[4];
    __shared__ float red2[2];
    const int b = blockIdx.x;
    const int n = n0 + b;
    if (n >= n1) return;
    const int h = threadIdx.x;
    const int w = h >> 6;
    const float xsv = xs[(size_t)n*HD+h];
    float xc = xwF[(size_t)b*HD+h] + swF[(size_t)b*HD+h] + bs[h];
    float s1=xc, s2=xc*xc;
#pragma unroll
    for (int off=1; off<64; off<<=1){ s1+=__shfl_xor(s1,off,64); s2+=__shfl_xor(s2,off,64); }
    if ((h&63)==0){ red[w*2]=s1; red[w*2+1]=s2; }
    __syncthreads();
    s1=red[0]+red[2]; s2=red[1]+red[3];
    float mu=s1*(1.f/128.f);
    float var=fmaxf(s2*(1.f/128.f)-mu*mu, 0.f);
    float xn=(xc-mu)*rsqrtf(var+1e-5f)*lng[h]+lnb[h];
    float ov0=xvO[(size_t)n*3*HD+h];
    float ov1=xvO[(size_t)n*3*HD+HD+h];
    float ov2=xvO[(size_t)n*3*HD+2*HD+h];
    float a0=avC[(size_t)b*3*HD+h];
    float a1=avC[(size_t)b*3*HD+HD+h];
    float a2=avC[(size_t)b*3*HD+2*HD+h];
    float d0s=sdC[b*3], d1s=sdC[b*3+1], d2s=sdC[b*3+2];
    float b2v=bv2[h];
    float v0=ov0+a0+gF[(size_t)(b*3+0)*HD+h]+b2v*d0s;
    float v1=ov1+a1+gF[(size_t)(b*3+1)*HD+h]+b2v*d1s;
    float v2=ov2+a2+gF[(size_t)(b*3+2)*HD+h]+b2v*d2s;
    float q=v0*v0+v1*v1+v2*v2;
#pragma unroll
    for (int off=1; off<64; off<<=1) q+=__shfl_xor(q,off,64);
    if ((h&63)==0) red2[w]=q;
    __syncthreads();
    q=fmaxf(red2[0]+red2[1], 0.f);
    float nrm=sqrtf(q*(1.f/128.f)+1e-5f);
    float scale=vsg[h]*sigm_(xn)/nrm;
    float r0=v0*scale, r1=v1*scale, r2=v2*scale;
    float nxs=silu_(xn);
    if (addRes){ nxs+=xsv; r0+=ov0; r1+=ov1; r2+=ov2; }
    xs[(size_t)n*HD+h]=nxs;
    xvN[(size_t)n*3*HD+h]=r0;
    xvN[(size_t)n*3*HD+HD+h]=r1;
    xvN[(size_t)n*3*HD+2*HD+h]=r2;
}

// ---------------- CSR build ----------------
__global__ void hist_kernel(const int* __restrict__ idx, int* __restrict__ cnt, int n, int nb){
    int i = blockIdx.x*256 + threadIdx.x;
    if (i < n){
        int v = idx[i]; v = min(max(v,0), nb-1);
        atomicAdd(&cnt[v], 1);
    }
}

// parallel 3-phase exclusive scan: block-local inclusive scan + block sums
__global__ __launch_bounds__(256)
void scan_blk(const int* __restrict__ cnt, int* __restrict__ rowptr,
              int* __restrict__ bsum, int n){
    const int b = blockIdx.x, t = threadIdx.x;
    const int i = b*256 + t;
    const int lane = t & 63, w = t >> 6;
    int v = (i < n) ? cnt[i] : 0;
    int s = v;
#pragma unroll
    for (int off=1; off<64; off<<=1){
        int u = __shfl_up(s, off, 64);
        if (lane >= off) s += u;
    }
    __shared__ int ws[4];
    if (lane == 63) ws[w] = s;
    __syncthreads();
    int add = 0;
#pragma unroll
    for (int j=0;j<4;++j) if (j < w) add += ws[j];
    s += add;
    if (i < n) rowptr[i+1] = s;          // inclusive scan -> exclusive via +1 shift
    if (t == 255) bsum[b] = s;           // padded lanes add 0, so this is the block total
    if (b == 0 && t == 0) rowptr[0] = 0;
}

// exclusive scan of block sums (nb <= 256)
__global__ __launch_bounds__(256)
void scan_bsum(int* __restrict__ bsum, int nb){
    const int t = threadIdx.x;
    const int lane = t & 63, w = t >> 6;
    int v = (t < nb) ? bsum[t] : 0;
    int s = v;
#pragma unroll
    for (int off=1; off<64; off<<=1){
        int u = __shfl_up(s, off, 64);
        if (lane >= off) s += u;
    }
    __shared__ int ws[4];
    if (lane == 63) ws[w] = s;
    __syncthreads();
    int add = 0;
#pragma unroll
    for (int j=0;j<4;++j) if (j < w) add += ws[j];
    s += add;
    if (t < nb) bsum[t] = s - v;         // exclusive
}

__global__ __launch_bounds__(256)
void scan_fix(int* __restrict__ rowptr, const int* __restrict__ bsum, int n){
    const int b = blockIdx.x, t = threadIdx.x;
    const int i = b*256 + t;
    const int off = bsum[b];
    if (i < n) rowptr[i+1] += off;       // i==n-1 covers rowptr[n]
}

__global__ void fill_kernel(const int* __restrict__ src, const int* __restrict__ dst,
                            const int* __restrict__ rowptr, int* __restrict__ cur,
                            int* __restrict__ elist, int* __restrict__ srcp,
                            int* __restrict__ dstp, int n){
    int e = blockIdx.x*256 + threadIdx.x;
    if (e < n){
        int d = dst[e]; d = min(max(d,0), NN-1);
        int slot = atomicAdd(&cur[d], 1);
        int p = rowptr[d] + slot;
        if (p >= 0 && p < NE){
            elist[p] = e;
            int s = src[e];
            srcp[p] = min(max(s,0), NN-1);
            dstp[p] = d;
        }
    }
}

__global__ void gptr_kernel(const int* __restrict__ batch, int* __restrict__ gptr){
    int n = blockIdx.x*256 + threadIdx.x;
    if (n >= NN) return;
    int b = batch[n]; b = min(max(b,0), NB-1);
    if (n == 0){
        for (int g=0; g<=b; ++g) gptr[g] = 0;
    } else {
        int bp = batch[n-1]; bp = min(max(bp,0), NB-1);
        for (int g=bp+1; g<=b; ++g) gptr[g] = n;
    }
    if (n == NN-1){
        for (int g=b+1; g<=NB; ++g) gptr[g] = NN;
    }
}

__global__ void xv_init(const float* __restrict__ xw, const float* __restrict__ pos,
                        float* __restrict__ xv){
    int n = blockIdx.x, h = threadIdx.x;
    float v = xw[(size_t)n*HD+h];
    xv[(size_t)n*3*HD + h]        = v*pos[n*3+0];
    xv[(size_t)n*3*HD + HD + h]   = v*pos[n*3+1];
    xv[(size_t)n*3*HD + 2*HD + h] = v*pos[n*3+2];
}

__global__ __launch_bounds__(128)
void capsule2(const float* __restrict__ Pf, const float* __restrict__ xv,
              const float* __restrict__ pvW, bf16* __restrict__ u){
    __shared__ float Pn[128];
    __shared__ float Xv[3][128];
    __shared__ float dots[48];
    __shared__ float pvn[16];
    __shared__ float capn2[8];
    int n = blockIdx.x, t = threadIdx.x;
    Pn[t] = Pf[(size_t)n*HD + t];
    Xv[0][t] = xv[(size_t)n*3*HD + t];
    Xv[1][t] = xv[(size_t)n*3*HD + HD + t];
    Xv[2][t] = xv[(size_t)n*3*HD + 2*HD + t];
    __syncthreads();
    if (t < 48){
        int pp = t/3, c = t%3;
        float a = 0.f;
        for (int hh=0; hh<128; ++hh) a += Xv[c][hh]*pvW[hh*16+pp];
        dots[t] = a;
    }
    if (t < 8){
        float a = 0.f;
        for (int d=0; d<16; ++d){ float x = Pn[t*16+d]; a += x*x; }
        capn2[t] = a;
    }
    __syncthreads();
    if (t < 16){
        float a = dots[t*3]*dots[t*3] + dots[t*3+1]*dots[t*3+1] + dots[t*3+2]*dots[t*3+2];
        pvn[t] = sqrtf(a + 1e-9f);
    }
    __syncthreads();
    int cap = t >> 4, d = t & 15;
    float n2 = capn2[cap];
    float pcv = Pn[t] * (n2/(1.f+n2)) * rsqrtf(n2 + 1e-9f);
    u[(size_t)n*HD + t] = __float2bfloat16(pcv + pvn[d]);
}

// two-stage pooling: slice WITHIN each graph's node range
__global__ void pool1(const int* __restrict__ gptr, const bf16* __restrict__ u,
                      float* __restrict__ Up){
    int blk = blockIdx.x;            // b*PSL + s
    int b = blk / PSL, s = blk % PSL;
    int h = threadIdx.x;
    int g0 = gptr[b], g1 = gptr[b+1];
    g0 = min(max(g0,0), NN); g1 = min(max(g1,0), NN);
    int len = g1 - g0;
    int lo = g0 + (int)(((long long)len * s) / PSL);
    int hi = g0 + (int)(((long long)len * (s+1)) / PSL);
    float a = 0.f;
    for (int n=lo; n<hi; ++n) a += bf2f(u[(size_t)n*HD + h]);
    Up[(size_t)blk*HD + h] = a;
}

__global__ void pool2(const float* __restrict__ Up, float* __restrict__ U){
    int b = blockIdx.x, h = threadIdx.x;
    float a = 0.f;
    for (int s=0; s<PSL; ++s) a += Up[(size_t)(b*PSL+s)*HD + h];
    U[b*HD + h] = a;
}

__global__ void graph_head(const float* __restrict__ U, const float* __restrict__ sW,
                           const float* __restrict__ aW, const float* __restrict__ ab,
                           const float* __restrict__ pW1, const float* __restrict__ pb1,
                           const float* __restrict__ pg1, const float* __restrict__ pbe1,
                           const float* __restrict__ pW2, const float* __restrict__ pb2,
                           const float* __restrict__ pg2, const float* __restrict__ pbe2,
                           const float* __restrict__ pW3, const float* __restrict__ pb3,
                           float* __restrict__ out){
    __shared__ float Ub[128];
    __shared__ float pooled[2048];
    __shared__ float vv[256];
    __shared__ float bbs[64], ccs[64];
    __shared__ float lg[8], aws[8];
    __shared__ float wcs[32];
    __shared__ float h1[64], h2[32];
    int b = blockIdx.x, t = threadIdx.x;
    if (t < 128) Ub[t] = U[b*HD + t];
    __syncthreads();
#pragma unroll
    for (int j=0;j<8;++j){
        int o = t + 256*j;
        int p = o >> 8, c = (o >> 5) & 7, e = o & 31;
        float a = 0.f;
#pragma unroll
        for (int d=0; d<16; ++d) a += Ub[p*16+d]*sW[((p*16+d)*8+c)*32+e];
        pooled[o] = a;
    }
    __syncthreads();
    {
        float s = 0.f;
        for (int p=0;p<8;++p) s += pooled[p*256 + t];
        s *= 0.125f;
        float n2 = s*s;
#pragma unroll
        for (int off=1; off<32; off<<=1) n2 += __shfl_xor(n2,off,32);
        vv[t] = s*(n2/(1.f+n2))*rsqrtf(n2+1e-9f);
    }
    __syncthreads();
    if (t < 64){
        int p = t>>3, c = t&7;
        float a = 0.f;
        for (int e=0;e<32;++e) a += pooled[p*256+c*32+e]*vv[c*32+e];
        bbs[t] = a;
    }
    __syncthreads();
    if (t < 64){
        int p = t>>3;
        float mx = -1e30f;
        for (int j=0;j<8;++j) mx = fmaxf(mx, bbs[p*8+j]);
        float sum = 0.f;
        for (int j=0;j<8;++j) sum += __expf(bbs[p*8+j]-mx);
        ccs[t] = __expf(bbs[t]-mx)/sum;
    }
    __syncthreads();
    {
        int c = t>>5;
        float s = 0.f;
        for (int p=0;p<8;++p) s += ccs[p*8+c]*pooled[p*256 + t];
        float n2 = s*s;
#pragma unroll
        for (int off=1; off<32; off<<=1) n2 += __shfl_xor(n2,off,32);
        vv[t] = s*(n2/(1.f+n2))*rsqrtf(n2+1e-9f);
    }
    __syncthreads();
    if (t < 8){
        float a = 0.f;
        for (int j=0;j<16;++j) a += vv[t*32+j]*aW[j];
        lg[t] = a + ab[0];
    }
    __syncthreads();
    if (t < 8){
        float mx = -1e30f;
        for (int j=0;j<8;++j) mx = fmaxf(mx, lg[j]);
        float sum = 0.f;
        for (int j=0;j<8;++j) sum += __expf(lg[j]-mx);
        aws[t] = __expf(lg[t]-mx)/sum;
    }
    __syncthreads();
    if (t < 32){
        float a = 0.f;
        for (int c=0;c<8;++c) a += aws[c]*vv[c*32+t];
        wcs[t] = a;
    }
    __syncthreads();
    if (t < 64){
        float a = 0.f;
        for (int e=0;e<32;++e) a += wcs[e]*pW1[e*64+t];
        h1[t] = silu_((a+pb1[t])*pg1[t]+pbe1[t]);
    }
    __syncthreads();
    if (t < 32){
        float a = 0.f;
        for (int j=0;j<64;++j) a += h1[j]*pW2[j*32+t];
        h2[t] = silu_((a+pb2[t])*pg2[t]+pbe2[t]);
    }
    __syncthreads();
    if (t == 0){
        float a = 0.f;
        for (int j=0;j<32;++j) a += h2[j]*pW3[j];
        a += pb3[0];
        if (!finite_(a)) a = 999.f;
        out[b] = a;
    }
}

__global__ void sentinel_k(float* __restrict__ out, float v){
    out[threadIdx.x] = v;
}

// ---------------- host side ----------------
extern "C" void kernel_launch(void* const* d_in, const int* in_sizes, int n_in,
                              void* d_out, int out_size, void* d_ws, size_t ws_size,
                              hipStream_t stream)
{
    (void)in_sizes; (void)n_in; (void)out_size;
    const float* x    = (const float*)d_in[0];
    const float* eat  = (const float*)d_in[1];
    const float* pos  = (const float*)d_in[2];
    const int*  eidx  = (const int*)d_in[3];
    const int*  batch = (const int*)d_in[4];
    const float* neW1=(const float*)d_in[5],  *neb1=(const float*)d_in[6],
               * neg1=(const float*)d_in[7],  *nebe1=(const float*)d_in[8];
    const float* neW2=(const float*)d_in[9],  *neb2=(const float*)d_in[10],
               * neg2=(const float*)d_in[11], *nebe2=(const float*)d_in[12];
    const float* eeW1=(const float*)d_in[13], *eeb1=(const float*)d_in[14];
    const float* eeW2=(const float*)d_in[15], *eeb2=(const float*)d_in[16];
    const float* ivW =(const float*)d_in[17], *ivb =(const float*)d_in[18];
    const float* cWma=(const float*)d_in[19], *cWmb=(const float*)d_in[20],
               * cWme=(const float*)d_in[21], *cbm =(const float*)d_in[22];
    const float* cWsx=(const float*)d_in[23], *cWsa=(const float*)d_in[24],
               * cbs =(const float*)d_in[25];
    const float* cWv1=(const float*)d_in[26], *cbv1=(const float*)d_in[27],
               * cWv2=(const float*)d_in[28], *cbv2=(const float*)d_in[29];
    const float* lng =(const float*)d_in[30], *lnb =(const float*)d_in[31],
               * vsg =(const float*)d_in[32];
    const float* pcW =(const float*)d_in[33], *pcb =(const float*)d_in[34];
    const float* pvW =(const float*)d_in[35];
    const float* sW  =(const float*)d_in[36];
    const float* aW  =(const float*)d_in[37], *ab  =(const float*)d_in[38];
    const float* pW1 =(const float*)d_in[39], *pb1 =(const float*)d_in[40],
               * pg1 =(const float*)d_in[41], *pbe1=(const float*)d_in[42];
    const float* pW2 =(const float*)d_in[43], *pb2 =(const float*)d_in[44],
               * pg2 =(const float*)d_in[45], *pbe2=(const float*)d_in[46];
    const float* pW3 =(const float*)d_in[47], *pb3 =(const float*)d_in[48];

    const int* src = eidx;
    const int* dst = eidx + NE;

    char* wp = (char*)d_ws;
    auto alloc = [&](size_t bytes)->char*{
        char* p = wp;
        wp += (bytes + 255) & ~(size_t)255;
        return p;
    };
    bf16*  bufM  = (bf16*) alloc((size_t)ECM*HD*2);
    bf16*  bufG  = (bf16*) alloc((size_t)ECM*HD*2);
    float* xs    = (float*)alloc((size_t)NN*HD*4);
    float* xvA   = (float*)alloc((size_t)NN*3*HD*4);
    float* xvB   = (float*)alloc((size_t)NN*3*HD*4);
    bf16*  An    = (bf16*) alloc((size_t)NN*HD*2);
    bf16*  Bn    = (bf16*) alloc((size_t)NN*HD*2);
    float* smC   = (float*)alloc((size_t)CN*HD*4);
    float* mdC   = (float*)alloc((size_t)CN*3*HD*4);
    float* avC   = (float*)alloc((size_t)CN*3*HD*4);
    float* sdC   = (float*)alloc((size_t)CN*3*4);
    bf16*  WtH   = (bf16*) alloc((size_t)7*HD*HD*2);
    bf16*  WtL   = (bf16*) alloc((size_t)7*HD*HD*2);
    bf16*  W1h   = (bf16*) alloc((size_t)HD*64*2);
    bf16*  W1l   = (bf16*) alloc((size_t)HD*64*2);
    float* Up    = (float*)alloc((size_t)NB*PSL*HD*4);
    float* Ubuf  = (float*)alloc((size_t)NB*HD*4);
    int* rowptr  = (int*)alloc((size_t)(NN+1)*4);
    int* cnt     = (int*)alloc((size_t)NN*4);
    int* bsum    = (int*)alloc((size_t)256*4);
    int* elist   = (int*)alloc((size_t)NE*4);
    int* srcp    = (int*)alloc((size_t)NE*4);
    int* dstp    = (int*)alloc((size_t)NE*4);
    int* gptr    = (int*)alloc((size_t)(NB+1)*4);
    size_t used  = (size_t)(wp - (char*)d_ws);   // ~249 MiB

    if (used > ws_size){
        sentinel_k<<<1, NB, 0, stream>>>((float*)d_out, -1.f - (float)(ws_size >> 20));
        return;
    }
    float* tmpF = xvB;
    bf16*  ubuf = An;
    float* Pf   = xvA;
    // nu-stage GEMM outputs overlay bufM/bufG (dead between scatter_c(c) and edge_pipe(c+1)):
    float* gF  = (float*)bufM;
    float* swF = gF  + (size_t)3*CN*HD;
    float* xwF = swF + (size_t)CN*HD;

    // ---- CSR + gptr + weight splits ----
    hipMemsetAsync(cnt, 0, (size_t)NN*4, stream);
    hist_kernel<<<(NE+255)/256, 256, 0, stream>>>(dst, cnt, NE, NN);
    const int SBLK = (NN+255)/256;   // 196 blocks
    scan_blk<<<SBLK, 256, 0, stream>>>(cnt, rowptr, bsum, NN);
    scan_bsum<<<1, 256, 0, stream>>>(bsum, SBLK);
    scan_fix<<<SBLK, 256, 0, stream>>>(rowptr, bsum, NN);
    hipMemsetAsync(cnt, 0, (size_t)NN*4, stream);
    fill_kernel<<<(NE+255)/256, 256, 0, stream>>>(src, dst, rowptr, cnt, elist, srcp, dstp, NE);
    gptr_kernel<<<(NN+255)/256, 256, 0, stream>>>(batch, gptr);
    wprep1<<<32,256,0,stream>>>(eeW1, W1h, W1l);
    wprep<<<64,256,0,stream>>>(eeW2, WtH, WtL);
    for (int l=0;l<3;++l){
        wprep<<<64,256,0,stream>>>(cWme + (size_t)l*HD*HD, WtH + (size_t)(1+l)*HD*HD,
                                   WtL + (size_t)(1+l)*HD*HD);
        wprep<<<64,256,0,stream>>>(cWv1 + (size_t)l*HD*HD, WtH + (size_t)(4+l)*HD*HD,
                                   WtL + (size_t)(4+l)*HD*HD);
    }

    const int GN = (NN+63)/64;
    const int GE = ECM/64;
    const int G3 = ((3*CN+63)/64) + 2*((CN+63)/64);

    // ---- node embeddings ----
    gemmk<M_BNSILU><<<GN,256,0,stream>>>(x, neW1, neb1, neg1, nebe1, tmpF, 0, NN, 92);
    gemmk<M_BNSILU><<<GN,256,0,stream>>>(tmpF, neW2, neb2, neg2, nebe2, xs, 0, NN, 128);
    gemmk<M_BIAS><<<GN,256,0,stream>>>(xs, ivW, ivb, nullptr, nullptr, tmpF, 0, NN, 128);
    xv_init<<<NN, 128, 0, stream>>>(tmpF, pos, xvA);

    // ---- message-passing layers ----
    float* xvO = xvA;
    float* xvN = xvB;
    for (int l=0; l<3; ++l){
        const float* Wma = cWma + (size_t)l*HD*HD;
        const float* Wmb = cWmb + (size_t)l*HD*HD;
        const float* bm  = cbm  + (size_t)l*HD;
        const float* Wsx = cWsx + (size_t)l*HD*HD;
        const float* Wsa = cWsa + (size_t)l*HD*HD;
        const float* bs  = cbs  + (size_t)l*HD;
        const float* bv1 = cbv1 + (size_t)l*HD;
        const float* Wv2 = cWv2 + (size_t)l*HD*HD;
        const float* bv2 = cbv2 + (size_t)l*HD;
        const bf16* Wmeh = WtH + (size_t)(1+l)*HD*HD;
        const bf16* Wmel = WtL + (size_t)(1+l)*HD*HD;
        const bf16* Wv1h = WtH + (size_t)(4+l)*HD*HD;
        const bf16* Wv1l = WtL + (size_t)(4+l)*HD*HD;

        gemmk<M_PLAIN><<<GN,256,0,stream>>>(xs, Wma, nullptr, nullptr, nullptr, An, 1, NN, 128);
        gemmk<M_PLAIN><<<GN,256,0,stream>>>(xs, Wmb, nullptr, nullptr, nullptr, Bn, 1, NN, 128);

        for (int c=0; c<NCH; ++c){
            int n0 = c*CN, n1 = n0+CN;
            edge_pipe<<<GE,256,0,stream>>>(eat, elist, srcp, dstp,
                                           W1h, W1l, eeb1,
                                           WtH, WtL, eeb2,
                                           Wmeh, Wmel, bm,
                                           An, Bn,
                                           Wv1h, Wv1l, bv1,
                                           rowptr, n0, n1, bufM, bufG);
            scatter_c<<<CN,128,0,stream>>>(rowptr, srcp, pos, bufM, bufG, xvO,
                                           smC, mdC, avC, sdC, n0, n1);
            gemm3<<<G3,256,0,stream>>>(mdC, Wv2, gF, 3*CN,
                                       smC, Wsa, swF, CN,
                                       xs + (size_t)n0*HD, Wsx, xwF, CN);
            nu_lite<<<CN,128,0,stream>>>(gF, swF, xwF, avC, sdC,
                                         xvO, xvN, xs,
                                         bv2, bs,
                                         lng + (size_t)l*HD, lnb + (size_t)l*HD,
                                         vsg + (size_t)l*HD, l>0 ? 1 : 0, n0, n1);
        }
        float* t = xvO; xvO = xvN; xvN = t;
    }

    // ---- capsules & head ----
    gemmk<M_BIAS><<<GN,256,0,stream>>>(xs, pcW, pcb, nullptr, nullptr, Pf, 0, NN, 128);
    capsule2<<<NN, 128, 0, stream>>>(Pf, xvO, pvW, ubuf);
    pool1<<<NB*PSL, 128, 0, stream>>>(gptr, ubuf, Up);
    pool2<<<NB, 128, 0, stream>>>(Up, Ubuf);
    graph_head<<<NB, 256, 0, stream>>>(Ubuf, sW, aW, ab,
                                       pW1, pb1, pg1, pbe1,
                                       pW2, pb2, pg2, pbe2,
                                       pW3, pb3, (float*)d_out);
}

// Round 6
// 3277.900 us; speedup vs baseline: 1.0605x; 1.0169x over previous
//
#include <hip/hip_runtime.h>
#include <hip/hip_bf16.h>
#include <math.h>

#define NN 50000
#define NE 400000
#define HD 128
#define NB 64
#define NCH 8
#define CN 6250          // nodes per chunk
#define ECM 53248        // max edges per chunk
#define PSL 16           // pool slices

typedef __hip_bfloat16 bf16;
typedef __attribute__((ext_vector_type(4))) unsigned short us4;
typedef __attribute__((ext_vector_type(8))) short s8v;    // 8 bf16 MFMA frag
typedef __attribute__((ext_vector_type(4))) float f4v;    // MFMA accumulator

__device__ __forceinline__ float sigm_(float x){ return 1.f/(1.f+__expf(-x)); }
__device__ __forceinline__ float silu_(float x){ return x*sigm_(x); }
__device__ __forceinline__ float bf2f(bf16 x){ return __bfloat162float(x); }
__device__ __forceinline__ unsigned short f2bu(float f){
    bf16 h = __float2bfloat16(f);
    return *reinterpret_cast<unsigned short*>(&h);
}
__device__ __forceinline__ bool finite_(float v){ return fabsf(v) <= 1e37f; }

enum { M_PLAIN=0, M_BIAS, M_BNSILU };

// ---------------- split-transpose weight prep ----------------
__global__ void wprep(const float* __restrict__ W, bf16* __restrict__ H, bf16* __restrict__ L){
    int i = blockIdx.x*256 + threadIdx.x;
    int k = i >> 7, n = i & 127;
    float w = W[i];
    bf16 h = __float2bfloat16(w);
    float r = w - bf2f(h);
    H[n*128 + k] = h;
    L[n*128 + k] = __float2bfloat16(r);
}

__global__ void wprep1(const float* __restrict__ W, bf16* __restrict__ H, bf16* __restrict__ L){
    int i = blockIdx.x*256 + threadIdx.x;
    int n = i >> 6, k = i & 63;
    float w = (k < 41) ? W[(size_t)k*HD + n] : 0.f;
    bf16 h = __float2bfloat16(w);
    float r = w - bf2f(h);
    H[n*64 + k] = h;
    L[n*64 + k] = __float2bfloat16(r);
}

// ---------------- generic tiled GEMM ----------------
template<int MODE>
__global__ __launch_bounds__(256)
void gemmk(const float* __restrict__ A, const float* __restrict__ W,
           const float* __restrict__ bias, const float* __restrict__ gg,
           const float* __restrict__ be, void* __restrict__ Cv, int owf, int M, int K)
{
    const int row0 = blockIdx.x * 64;
    if (row0 >= M) return;
    __shared__ float As[32][68];
    __shared__ float Ws[32][128];
    const int tid = threadIdx.x;
    const int tx = tid & 15, ty = tid >> 4;
    const int col0 = tx*8;
    float acc[4][8];
#pragma unroll
    for (int r=0;r<4;++r)
#pragma unroll
        for (int j=0;j<8;++j) acc[r][j]=0.f;
    const int mload = tid >> 2;
    const int kload = (tid & 3) << 3;
    const int grow = row0 + mload;
    const bool rv = grow < M;

    for (int k0 = 0; k0 < K; k0 += 32) {
        if (rv && ((K & 3) == 0) && (k0 + kload + 8 <= K)) {
            const float* ap = A + (size_t)grow*K + k0 + kload;
            float4 v0 = *(const float4*)ap;
            float4 v1 = *(const float4*)(ap+4);
            As[kload+0][mload]=v0.x; As[kload+1][mload]=v0.y;
            As[kload+2][mload]=v0.z; As[kload+3][mload]=v0.w;
            As[kload+4][mload]=v1.x; As[kload+5][mload]=v1.y;
            As[kload+6][mload]=v1.z; As[kload+7][mload]=v1.w;
        } else {
#pragma unroll
            for (int j=0;j<8;++j){
                int kg = k0 + kload + j;
                As[kload+j][mload] = (rv && kg<K) ? A[(size_t)grow*K+kg] : 0.f;
            }
        }
        if (k0 + 32 <= K) {
#pragma unroll
            for (int j=0;j<4;++j){
                int el = (tid + j*256)*4;
                int kk = el >> 7, col = el & 127;
                *(float4*)&Ws[kk][col] = *(const float4*)&W[(size_t)(k0+kk)*HD + col];
            }
        } else {
#pragma unroll
            for (int j=0;j<16;++j){
                int el = tid*16 + j;
                int kk = el >> 7, col = el & 127;
                int kg = k0 + kk;
                Ws[kk][col] = (kg < K) ? W[(size_t)kg*HD + col] : 0.f;
            }
        }
        __syncthreads();
#pragma unroll
        for (int k=0;k<32;++k){
            float4 a4 = *(const float4*)&As[k][ty*4];
            float4 w0 = *(const float4*)&Ws[k][col0];
            float4 w1 = *(const float4*)&Ws[k][col0+4];
            float av[4] = {a4.x,a4.y,a4.z,a4.w};
            float wv[8] = {w0.x,w0.y,w0.z,w0.w,w1.x,w1.y,w1.z,w1.w};
#pragma unroll
            for (int r=0;r<4;++r)
#pragma unroll
                for (int j=0;j<8;++j) acc[r][j] += av[r]*wv[j];
        }
        __syncthreads();
    }
#pragma unroll
    for (int r=0;r<4;++r){
        int orow = row0 + ty*4 + r;
        if (orow >= M) continue;
        float o[8];
#pragma unroll
        for (int j=0;j<8;++j) o[j]=acc[r][j];
        if constexpr (MODE==M_BIAS || MODE==M_BNSILU){
#pragma unroll
            for (int j=0;j<8;++j) o[j] += bias[col0+j];
        }
        if constexpr (MODE==M_BNSILU){
#pragma unroll
            for (int j=0;j<8;++j) o[j] = silu_(o[j]*gg[col0+j] + be[col0+j]);
        }
        if (owf){
            bf16* C = (bf16*)Cv;
#pragma unroll
            for (int j=0;j<8;++j) C[(size_t)orow*HD+col0+j] = __float2bfloat16(o[j]);
        } else {
            float* C = (float*)Cv;
            float4* cp = (float4*)&C[(size_t)orow*HD + col0];
            cp[0] = make_float4(o[0],o[1],o[2],o[3]);
            cp[1] = make_float4(o[4],o[5],o[6],o[7]);
        }
    }
}

// ---------------- fused 3-GEMM (K=128, f32, no bias) for the nu stage ----------------
__global__ __launch_bounds__(256)
void gemm3(const float* __restrict__ A0, const float* __restrict__ W0, float* __restrict__ C0, int M0,
           const float* __restrict__ A1, const float* __restrict__ W1, float* __restrict__ C1, int M1,
           const float* __restrict__ A2, const float* __restrict__ W2, float* __restrict__ C2, int M2)
{
    const int nb0 = (M0+63)>>6, nb1 = (M1+63)>>6;
    int bb = (int)blockIdx.x;
    const float *A, *W; float* C; int M;
    if (bb < nb0){ A=A0; W=W0; C=C0; M=M0; }
    else if (bb < nb0+nb1){ bb -= nb0; A=A1; W=W1; C=C1; M=M1; }
    else { bb -= nb0+nb1; A=A2; W=W2; C=C2; M=M2; }
    const int row0 = bb*64;

    __shared__ float As[32][68];
    __shared__ float Ws[32][128];
    const int tid = threadIdx.x;
    const int tx = tid & 15, ty = tid >> 4;
    const int col0 = tx*8;
    float acc[4][8];
#pragma unroll
    for (int r=0;r<4;++r)
#pragma unroll
        for (int j=0;j<8;++j) acc[r][j]=0.f;
    const int mload = tid >> 2;
    const int kload = (tid & 3) << 3;
    const int grow = row0 + mload;
    const bool rv = grow < M;

    for (int k0 = 0; k0 < 128; k0 += 32) {
        if (rv) {
            const float* ap = A + (size_t)grow*128 + k0 + kload;
            float4 v0 = *(const float4*)ap;
            float4 v1 = *(const float4*)(ap+4);
            As[kload+0][mload]=v0.x; As[kload+1][mload]=v0.y;
            As[kload+2][mload]=v0.z; As[kload+3][mload]=v0.w;
            As[kload+4][mload]=v1.x; As[kload+5][mload]=v1.y;
            As[kload+6][mload]=v1.z; As[kload+7][mload]=v1.w;
        } else {
#pragma unroll
            for (int j=0;j<8;++j) As[kload+j][mload] = 0.f;
        }
#pragma unroll
        for (int j=0;j<4;++j){
            int el = (tid + j*256)*4;
            int kk = el >> 7, col = el & 127;
            *(float4*)&Ws[kk][col] = *(const float4*)&W[(size_t)(k0+kk)*HD + col];
        }
        __syncthreads();
#pragma unroll
        for (int k=0;k<32;++k){
            float4 a4 = *(const float4*)&As[k][ty*4];
            float4 w0 = *(const float4*)&Ws[k][col0];
            float4 w1 = *(const float4*)&Ws[k][col0+4];
            float av[4] = {a4.x,a4.y,a4.z,a4.w};
            float wv[8] = {w0.x,w0.y,w0.z,w0.w,w1.x,w1.y,w1.z,w1.w};
#pragma unroll
            for (int r=0;r<4;++r)
#pragma unroll
                for (int j=0;j<8;++j) acc[r][j] += av[r]*wv[j];
        }
        __syncthreads();
    }
#pragma unroll
    for (int r=0;r<4;++r){
        int orow = row0 + ty*4 + r;
        if (orow >= M) continue;
        float4* cp = (float4*)&C[(size_t)orow*HD + col0];
        cp[0] = make_float4(acc[r][0],acc[r][1],acc[r][2],acc[r][3]);
        cp[1] = make_float4(acc[r][4],acc[r][5],acc[r][6],acc[r][7]);
    }
}

// ---------------- MFMA fused edge pipeline ----------------
// round-3 structure; phase 1 An/Bn gathers replaced by register-prefetch
// (issued before the phase-1 MFMA loop, latency hidden under MFMA) + LDS
// transpose roundtrip through the dead T1/T2 windows.
__global__ __launch_bounds__(256)
void edge_pipe(const float* __restrict__ eat,
               const int* __restrict__ elist, const int* __restrict__ srcp,
               const int* __restrict__ dstp,
               const bf16* __restrict__ W1h, const bf16* __restrict__ W1l,
               const float* __restrict__ b1,
               const bf16* __restrict__ W2h, const bf16* __restrict__ W2l,
               const float* __restrict__ b2,
               const bf16* __restrict__ Wmeh, const bf16* __restrict__ Wmel,
               const float* __restrict__ bm,
               const bf16* __restrict__ An, const bf16* __restrict__ Bn,
               const bf16* __restrict__ Wv1h, const bf16* __restrict__ Wv1l,
               const float* __restrict__ bv1,
               const int* __restrict__ rp, int rn0, int rn1,
               bf16* __restrict__ outM, bf16* __restrict__ outG)
{
    __shared__ __align__(16) unsigned short T1[64][136];
    __shared__ __align__(16) unsigned short T2[64][136];
    __shared__ int elS[64], seS[64], deS[64];

    const int cbase = rp[rn0];
    const int Ml = min(ECM, max(rp[rn1]-cbase, 0));
    const int row0 = blockIdx.x*64;
    if (row0 >= Ml) return;
    const int tid = threadIdx.x;
    const int lane = tid & 63, wave = tid >> 6;
    const int quad = lane >> 4, n16 = lane & 15;
    const int cwb = wave*32;

    if (tid < 64){
        int r = row0 + tid;
        bool v = r < Ml;
        int p = cbase + (v ? r : 0);
        elS[tid] = v ? min(max(elist[p],0),NE-1) : 0;
        seS[tid] = v ? srcp[p] : 0;
        deS[tid] = v ? dstp[p] : 0;
    }
    __syncthreads();

    f4v acc[4][2];

    // ---------- G1: K=64(padded) split MFMA ----------
    {
        s8v B1h[2][2], B1l[2][2];
#pragma unroll
        for (int ct=0; ct<2; ++ct){
            int nn = cwb + ct*16 + n16;
#pragma unroll
            for (int kc=0; kc<2; ++kc){
                B1h[ct][kc] = *(const s8v*)&W1h[(size_t)nn*64 + kc*32 + quad*8];
                B1l[ct][kc] = *(const s8v*)&W1l[(size_t)nn*64 + kc*32 + quad*8];
            }
        }
#pragma unroll
        for (int rt=0;rt<4;++rt)
#pragma unroll
            for (int ct=0;ct<2;++ct) acc[rt][ct] = (f4v){0.f,0.f,0.f,0.f};

#pragma unroll
        for (int rt=0; rt<4; ++rt){
            int arow = elS[rt*16 + n16];
#pragma unroll
            for (int kc=0; kc<2; ++kc){
                s8v ah, al;
#pragma unroll
                for (int j=0;j<8;++j){
                    int k = kc*32 + quad*8 + j;
                    float v = (k < 41) ? eat[(size_t)arow*41 + k] : 0.f;
                    unsigned short h = f2bu(v);
                    ah[j] = (short)h;
                    al[j] = (short)f2bu(v - __uint_as_float(((unsigned)h)<<16));
                }
#pragma unroll
                for (int ct=0; ct<2; ++ct){
                    acc[rt][ct] = __builtin_amdgcn_mfma_f32_16x16x32_bf16(ah, B1h[ct][kc], acc[rt][ct], 0,0,0);
                    acc[rt][ct] = __builtin_amdgcn_mfma_f32_16x16x32_bf16(ah, B1l[ct][kc], acc[rt][ct], 0,0,0);
                    acc[rt][ct] = __builtin_amdgcn_mfma_f32_16x16x32_bf16(al, B1h[ct][kc], acc[rt][ct], 0,0,0);
                }
            }
        }
#pragma unroll
        for (int ct=0; ct<2; ++ct){
            int col = cwb + ct*16 + n16;
            float bc = b1[col];
#pragma unroll
            for (int rt=0; rt<4; ++rt)
#pragma unroll
                for (int i=0;i<4;++i)
                    T1[rt*16 + quad*4 + i][col] = f2bu(silu_(acc[rt][ct][i] + bc));
        }
    }
    __syncthreads();

    // ---------- phases 0..2 (K=128, split-bf16 weights) ----------
    s8v Bh[2][4], Bl[2][4];
    for (int ph=0; ph<3; ++ph){
        const bf16* WH = (ph==0)? W2h : (ph==1)? Wmeh : Wv1h;
        const bf16* WL = (ph==0)? W2l : (ph==1)? Wmel : Wv1l;
        const unsigned short (*Tin)[136] = (ph==1)? (const unsigned short(*)[136])T2
                                                  : (const unsigned short(*)[136])T1;
#pragma unroll
        for (int ct=0; ct<2; ++ct){
            int nn = cwb + ct*16 + n16;
            const s8v* hp = (const s8v*)&WH[(size_t)nn*128];
            const s8v* lp = (const s8v*)&WL[(size_t)nn*128];
#pragma unroll
            for (int kc=0; kc<4; ++kc){
                Bh[ct][kc] = hp[kc*4 + quad];
                Bl[ct][kc] = lp[kc*4 + quad];
            }
        }
#pragma unroll
        for (int rt=0;rt<4;++rt)
#pragma unroll
            for (int ct=0;ct<2;++ct) acc[rt][ct] = (f4v){0.f,0.f,0.f,0.f};

        // phase-1 prefetch: coalesced An/Bn rows into registers; latency is
        // hidden under the 64-MFMA loop below (no drain before first use).
        s8v anR[4], bnR[4];
        if (ph==1){
#pragma unroll
            for (int it=0; it<4; ++it){
                int idx = tid + it*256;       // 0..1023
                int r = idx >> 4, c = idx & 15;
                anR[it] = *(const s8v*)&An[(size_t)seS[r]*HD + c*8];
                bnR[it] = *(const s8v*)&Bn[(size_t)deS[r]*HD + c*8];
            }
        }

#pragma unroll
        for (int kc=0; kc<4; ++kc){
#pragma unroll
            for (int rt=0; rt<4; ++rt){
                s8v a = *(const s8v*)&Tin[rt*16 + n16][kc*32 + quad*8];
#pragma unroll
                for (int ct=0; ct<2; ++ct){
                    acc[rt][ct] = __builtin_amdgcn_mfma_f32_16x16x32_bf16(a, Bh[ct][kc], acc[rt][ct], 0,0,0);
                    acc[rt][ct] = __builtin_amdgcn_mfma_f32_16x16x32_bf16(a, Bl[ct][kc], acc[rt][ct], 0,0,0);
                }
            }
        }
        if (ph==0){
#pragma unroll
            for (int ct=0; ct<2; ++ct){
                int col = cwb + ct*16 + n16;
                float bc = b2[col];
#pragma unroll
                for (int rt=0; rt<4; ++rt)
#pragma unroll
                    for (int i=0;i<4;++i)
                        T2[rt*16 + quad*4 + i][col] = f2bu(silu_(acc[rt][ct][i] + bc));
            }
            __syncthreads();
        } else if (ph==1){
            __syncthreads();   // all waves done reading T2 (MFMA); T1 dead since phase-0 end
            // transpose-roundtrip the prefetched rows: An -> T1, Bn -> T2
#pragma unroll
            for (int it=0; it<4; ++it){
                int idx = tid + it*256;
                int r = idx >> 4, c = idx & 15;
                *(s8v*)&T1[r][c*8] = anR[it];
                *(s8v*)&T2[r][c*8] = bnR[it];
            }
            __syncthreads();
            // epilogue: each (row,col) slot is owned by exactly one thread, so
            // reading its An value from T1[row][col] and overwriting the same
            // slot with the output needs no extra barrier.
#pragma unroll
            for (int ct=0; ct<2; ++ct){
                int col = cwb + ct*16 + n16;
                float bc = bm[col];
#pragma unroll
                for (int rt=0; rt<4; ++rt)
#pragma unroll
                    for (int i=0;i<4;++i){
                        int row = rt*16 + quad*4 + i;
                        float v = silu_(acc[rt][ct][i] + bc
                                        + bf2f(*(const bf16*)&T1[row][col])
                                        + bf2f(*(const bf16*)&T2[row][col]));
                        T1[row][col] = f2bu(v);
                    }
            }
            __syncthreads();
            {
                int row = tid >> 2, seg = tid & 3;
                if (row0 + row < Ml){
                    const s8v* s = (const s8v*)&T1[row][seg*32];
                    s8v* d = (s8v*)&outM[(size_t)(row0+row)*HD + seg*32];
                    d[0]=s[0]; d[1]=s[1]; d[2]=s[2]; d[3]=s[3];
                }
            }
        } else {
#pragma unroll
            for (int ct=0; ct<2; ++ct){
                int col = cwb + ct*16 + n16;
                float bc = bv1[col];
#pragma unroll
                for (int rt=0; rt<4; ++rt)
#pragma unroll
                    for (int i=0;i<4;++i)
                        T2[rt*16 + quad*4 + i][col] = f2bu(acc[rt][ct][i] + bc);
            }
            __syncthreads();
            {
                int row = tid >> 2, seg = tid & 3;
                if (row0 + row < Ml){
                    const s8v* s = (const s8v*)&T2[row][seg*32];
                    s8v* d = (s8v*)&outG[(size_t)(row0+row)*HD + seg*32];
                    d[0]=s[0]; d[1]=s[1]; d[2]=s[2]; d[3]=s[3];
                }
            }
        }
    }
}

// ---------------- latency phase: per-node edge aggregation ----------------
__global__ __launch_bounds__(128)
void scatter_c(const int* __restrict__ rp, const int* __restrict__ srcp,
               const float* __restrict__ pos,
               const bf16* __restrict__ mB, const bf16* __restrict__ gB,
               const float* __restrict__ xvO,
               float* __restrict__ smC, float* __restrict__ mdC,
               float* __restrict__ avC, float* __restrict__ sdC, int n0, int n1)
{
    const int b = blockIdx.x;
    const int n = n0 + b;
    if (n >= n1) return;
    const int h = threadIdx.x;
    const int cbase = rp[n0];
    int p0 = rp[n], p1 = rp[n+1];
    float px0=pos[n*3],px1=pos[n*3+1],px2=pos[n*3+2];
    float sm=0,a0=0,a1=0,a2=0,m0=0,m1=0,m2=0,d0s=0,d1s=0,d2s=0;
    for (int p=p0;p<p1;++p){
        int ii=p-cbase; if ((unsigned)ii>=(unsigned)ECM) break;
        float mh=bf2f(mB[(size_t)ii*HD+h]);
        float gh=bf2f(gB[(size_t)ii*HD+h]);
        int sn=srcp[p]; sn=min(max(sn,0),NN-1);
        float d0=px0-pos[sn*3], d1=px1-pos[sn*3+1], d2=px2-pos[sn*3+2];
        sm+=mh;
        a0+=xvO[(size_t)sn*3*HD+h]*gh;
        a1+=xvO[(size_t)sn*3*HD+HD+h]*gh;
        a2+=xvO[(size_t)sn*3*HD+2*HD+h]*gh;
        m0+=mh*d0; m1+=mh*d1; m2+=mh*d2;
        d0s+=d0; d1s+=d1; d2s+=d2;
    }
    smC[(size_t)b*HD+h]=sm;
    mdC[(size_t)b*3*HD+h]=m0;
    mdC[(size_t)b*3*HD+HD+h]=m1;
    mdC[(size_t)b*3*HD+2*HD+h]=m2;
    avC[(size_t)b*3*HD+h]=a0;
    avC[(size_t)b*3*HD+HD+h]=a1;
    avC[(size_t)b*3*HD+2*HD+h]=a2;
    if (h==0){ sdC[b*3]=d0s; sdC[b*3+1]=d1s; sdC[b*3+2]=d2s; }
}

// ---------------- streaming epilogue: layernorm + equivariant update ----------------
__global__ __launch_bounds__(128)
void nu_lite(const float* __restrict__ gF, const float* __restrict__ swF,
             const float* __restrict__ xwF,
             const float* __restrict__ avC, const float* __restrict__ sdC,
             const float* __restrict__ xvO, float* __restrict__ xvN,
             float* __restrict__ xs,
             const float* __restrict__ bv2, const float* __restrict__ bs,
             const float* __restrict__ lng, const float* __restrict__ lnb,
             const float* __restrict__ vsg, int addRes, int n0, int n1)
{
    __shared__ float red[4];
    __shared__ float red2[2];
    const int b = blockIdx.x;
    const int n = n0 + b;
    if (n >= n1) return;
    const int h = threadIdx.x;
    const int w = h >> 6;
    const float xsv = xs[(size_t)n*HD+h];
    float xc = xwF[(size_t)b*HD+h] + swF[(size_t)b*HD+h] + bs[h];
    float s1=xc, s2=xc*xc;
#pragma unroll
    for (int off=1; off<64; off<<=1){ s1+=__shfl_xor(s1,off,64); s2+=__shfl_xor(s2,off,64); }
    if ((h&63)==0){ red[w*2]=s1; red[w*2+1]=s2; }
    __syncthreads();
    s1=red[0]+red[2]; s2=red[1]+red[3];
    float mu=s1*(1.f/128.f);
    float var=fmaxf(s2*(1.f/128.f)-mu*mu, 0.f);
    float xn=(xc-mu)*rsqrtf(var+1e-5f)*lng[h]+lnb[h];
    float ov0=xvO[(size_t)n*3*HD+h];
    float ov1=xvO[(size_t)n*3*HD+HD+h];
    float ov2=xvO[(size_t)n*3*HD+2*HD+h];
    float a0=avC[(size_t)b*3*HD+h];
    float a1=avC[(size_t)b*3*HD+HD+h];
    float a2=avC[(size_t)b*3*HD+2*HD+h];
    float d0s=sdC[b*3], d1s=sdC[b*3+1], d2s=sdC[b*3+2];
    float b2v=bv2[h];
    float v0=ov0+a0+gF[(size_t)(b*3+0)*HD+h]+b2v*d0s;
    float v1=ov1+a1+gF[(size_t)(b*3+1)*HD+h]+b2v*d1s;
    float v2=ov2+a2+gF[(size_t)(b*3+2)*HD+h]+b2v*d2s;
    float q=v0*v0+v1*v1+v2*v2;
#pragma unroll
    for (int off=1; off<64; off<<=1) q+=__shfl_xor(q,off,64);
    if ((h&63)==0) red2[w]=q;
    __syncthreads();
    q=fmaxf(red2[0]+red2[1], 0.f);
    float nrm=sqrtf(q*(1.f/128.f)+1e-5f);
    float scale=vsg[h]*sigm_(xn)/nrm;
    float r0=v0*scale, r1=v1*scale, r2=v2*scale;
    float nxs=silu_(xn);
    if (addRes){ nxs+=xsv; r0+=ov0; r1+=ov1; r2+=ov2; }
    xs[(size_t)n*HD+h]=nxs;
    xvN[(size_t)n*3*HD+h]=r0;
    xvN[(size_t)n*3*HD+HD+h]=r1;
    xvN[(size_t)n*3*HD+2*HD+h]=r2;
}

// ---------------- CSR build ----------------
__global__ void hist_kernel(const int* __restrict__ idx, int* __restrict__ cnt, int n, int nb){
    int i = blockIdx.x*256 + threadIdx.x;
    if (i < n){
        int v = idx[i]; v = min(max(v,0), nb-1);
        atomicAdd(&cnt[v], 1);
    }
}

// parallel 3-phase exclusive scan: block-local inclusive scan + block sums
__global__ __launch_bounds__(256)
void scan_blk(const int* __restrict__ cnt, int* __restrict__ rowptr,
              int* __restrict__ bsum, int n){
    const int b = blockIdx.x, t = threadIdx.x;
    const int i = b*256 + t;
    const int lane = t & 63, w = t >> 6;
    int v = (i < n) ? cnt[i] : 0;
    int s = v;
#pragma unroll
    for (int off=1; off<64; off<<=1){
        int u = __shfl_up(s, off, 64);
        if (lane >= off) s += u;
    }
    __shared__ int ws[4];
    if (lane == 63) ws[w] = s;
    __syncthreads();
    int add = 0;
#pragma unroll
    for (int j=0;j<4;++j) if (j < w) add += ws[j];
    s += add;
    if (i < n) rowptr[i+1] = s;          // inclusive scan -> exclusive via +1 shift
    if (t == 255) bsum[b] = s;           // padded lanes add 0, so this is the block total
    if (b == 0 && t == 0) rowptr[0] = 0;
}

// exclusive scan of block sums (nb <= 256)
__global__ __launch_bounds__(256)
void scan_bsum(int* __restrict__ bsum, int nb){
    const int t = threadIdx.x;
    const int lane = t & 63, w = t >> 6;
    int v = (t < nb) ? bsum[t] : 0;
    int s = v;
#pragma unroll
    for (int off=1; off<64; off<<=1){
        int u = __shfl_up(s, off, 64);
        if (lane >= off) s += u;
    }
    __shared__ int ws[4];
    if (lane == 63) ws[w] = s;
    __syncthreads();
    int add = 0;
#pragma unroll
    for (int j=0;j<4;++j) if (j < w) add += ws[j];
    s += add;
    if (t < nb) bsum[t] = s - v;         // exclusive
}

__global__ __launch_bounds__(256)
void scan_fix(int* __restrict__ rowptr, const int* __restrict__ bsum, int n){
    const int b = blockIdx.x, t = threadIdx.x;
    const int i = b*256 + t;
    const int off = bsum[b];
    if (i < n) rowptr[i+1] += off;       // i==n-1 covers rowptr[n]
}

__global__ void fill_kernel(const int* __restrict__ src, const int* __restrict__ dst,
                            const int* __restrict__ rowptr, int* __restrict__ cur,
                            int* __restrict__ elist, int* __restrict__ srcp,
                            int* __restrict__ dstp, int n){
    int e = blockIdx.x*256 + threadIdx.x;
    if (e < n){
        int d = dst[e]; d = min(max(d,0), NN-1);
        int slot = atomicAdd(&cur[d], 1);
        int p = rowptr[d] + slot;
        if (p >= 0 && p < NE){
            elist[p] = e;
            int s = src[e];
            srcp[p] = min(max(s,0), NN-1);
            dstp[p] = d;
        }
    }
}

__global__ void gptr_kernel(const int* __restrict__ batch, int* __restrict__ gptr){
    int n = blockIdx.x*256 + threadIdx.x;
    if (n >= NN) return;
    int b = batch[n]; b = min(max(b,0), NB-1);
    if (n == 0){
        for (int g=0; g<=b; ++g) gptr[g] = 0;
    } else {
        int bp = batch[n-1]; bp = min(max(bp,0), NB-1);
        for (int g=bp+1; g<=b; ++g) gptr[g] = n;
    }
    if (n == NN-1){
        for (int g=b+1; g<=NB; ++g) gptr[g] = NN;
    }
}

__global__ void xv_init(const float* __restrict__ xw, const float* __restrict__ pos,
                        float* __restrict__ xv){
    int n = blockIdx.x, h = threadIdx.x;
    float v = xw[(size_t)n*HD+h];
    xv[(size_t)n*3*HD + h]        = v*pos[n*3+0];
    xv[(size_t)n*3*HD + HD + h]   = v*pos[n*3+1];
    xv[(size_t)n*3*HD + 2*HD + h] = v*pos[n*3+2];
}

// ---------------- capsule: wave-per-node, all lanes active ----------------
// 16 groups x 4 lanes compute the 48 pv dots; pvW column slices live in
// registers (pre-rotated so all indices are compile-time); xv staged in
// padded LDS with per-lane stagger -> conflict-free reads.
__global__ __launch_bounds__(256)
void capsule2(const float* __restrict__ Pf, const float* __restrict__ xv,
              const float* __restrict__ pvW, bf16* __restrict__ u){
    __shared__ float XvS[4][3*132];          // per-wave staging, rows padded to 132
    const int tid  = threadIdx.x;
    const int wave = tid >> 6, lane = tid & 63;
    const int p = lane >> 2, l = lane & 3, l8 = (lane & 3) << 3;
    float* Xw = XvS[wave];

    // per-lane pvW slice: rotation matches the staggered LDS access below
    float pvr[32];
#pragma unroll
    for (int i = 0; i < 32; ++i){
        int h = l*32 + ((i + l8) & 31);
        pvr[i] = pvW[h*16 + p];
    }

    const int waveGlobal = blockIdx.x*4 + wave;     // 0..12499
#pragma unroll 1
    for (int it = 0; it < 4; ++it){
        int n = waveGlobal + it*12500;              // exact cover of 50000
        const float* xvn = xv + (size_t)n*3*HD;
        // coalesced stage of the node's 384 xv floats into padded LDS
#pragma unroll
        for (int k = 0; k < 6; ++k){
            int e = k*64 + lane;
            int c = e >> 7, hh = e & 127;
            Xw[c*132 + hh] = xvn[e];
        }
        float pn0 = Pf[(size_t)n*HD + lane];
        float pn1 = Pf[(size_t)n*HD + 64 + lane];
        __syncthreads();                            // writes visible (uniform trip count)
        float a0=0.f, a1=0.f, a2=0.f;
#pragma unroll
        for (int i = 0; i < 32; ++i){
            int hh = l*32 + ((i + l8) & 31);        // stagger -> distinct banks per l
            float w = pvr[i];
            a0 += Xw[hh]       * w;
            a1 += Xw[132 + hh] * w;
            a2 += Xw[264 + hh] * w;
        }
        // reduce within 4-lane group
        a0 += __shfl_xor(a0, 1, 64); a0 += __shfl_xor(a0, 2, 64);
        a1 += __shfl_xor(a1, 1, 64); a1 += __shfl_xor(a1, 2, 64);
        a2 += __shfl_xor(a2, 1, 64); a2 += __shfl_xor(a2, 2, 64);
        float pvn_own = sqrtf(a0*a0 + a1*a1 + a2*a2 + 1e-9f);
        float pvn_d = __shfl(pvn_own, (lane & 15) << 2, 64);   // pvn[t&15]
        // capn2 via 16-lane reduction of Pn^2
        float s0 = pn0*pn0, s1 = pn1*pn1;
#pragma unroll
        for (int off = 1; off < 16; off <<= 1){
            s0 += __shfl_xor(s0, off, 64);
            s1 += __shfl_xor(s1, off, 64);
        }
        float r0 = pn0 * (s0/(1.f+s0)) * rsqrtf(s0 + 1e-9f) + pvn_d;
        float r1 = pn1 * (s1/(1.f+s1)) * rsqrtf(s1 + 1e-9f) + pvn_d;
        u[(size_t)n*HD + lane]      = __float2bfloat16(r0);
        u[(size_t)n*HD + 64 + lane] = __float2bfloat16(r1);
        __syncthreads();                            // WAR: reads done before next stage
    }
}

// two-stage pooling: slice WITHIN each graph's node range
__global__ void pool1(const int* __restrict__ gptr, const bf16* __restrict__ u,
                      float* __restrict__ Up){
    int blk = blockIdx.x;            // b*PSL + s
    int b = blk / PSL, s = blk % PSL;
    int h = threadIdx.x;
    int g0 = gptr[b], g1 = gptr[b+1];
    g0 = min(max(g0,0), NN); g1 = min(max(g1,0), NN);
    int len = g1 - g0;
    int lo = g0 + (int)(((long long)len * s) / PSL);
    int hi = g0 + (int)(((long long)len * (s+1)) / PSL);
    float a = 0.f;
    for (int n=lo; n<hi; ++n) a += bf2f(u[(size_t)n*HD + h]);
    Up[(size_t)blk*HD + h] = a;
}

__global__ void pool2(const float* __restrict__ Up, float* __restrict__ U){
    int b = blockIdx.x, h = threadIdx.x;
    float a = 0.f;
    for (int s=0; s<PSL; ++s) a += Up[(size_t)(b*PSL+s)*HD + h];
    U[b*HD + h] = a;
}

__global__ void graph_head(const float* __restrict__ U, const float* __restrict__ sW,
                           const float* __restrict__ aW, const float* __restrict__ ab,
                           const float* __restrict__ pW1, const float* __restrict__ pb1,
                           const float* __restrict__ pg1, const float* __restrict__ pbe1,
                           const float* __restrict__ pW2, const float* __restrict__ pb2,
                           const float* __restrict__ pg2, const float* __restrict__ pbe2,
                           const float* __restrict__ pW3, const float* __restrict__ pb3,
                           float* __restrict__ out){
    __shared__ float Ub[128];
    __shared__ float pooled[2048];
    __shared__ float vv[256];
    __shared__ float bbs[64], ccs[64];
    __shared__ float lg[8], aws[8];
    __shared__ float wcs[32];
    __shared__ float h1[64], h2[32];
    int b = blockIdx.x, t = threadIdx.x;
    if (t < 128) Ub[t] = U[b*HD + t];
    __syncthreads();
#pragma unroll
    for (int j=0;j<8;++j){
        int o = t + 256*j;
        int p = o >> 8, c = (o >> 5) & 7, e = o & 31;
        float a = 0.f;
#pragma unroll
        for (int d=0; d<16; ++d) a += Ub[p*16+d]*sW[((p*16+d)*8+c)*32+e];
        pooled[o] = a;
    }
    __syncthreads();
    {
        float s = 0.f;
        for (int p=0;p<8;++p) s += pooled[p*256 + t];
        s *= 0.125f;
        float n2 = s*s;
#pragma unroll
        for (int off=1; off<32; off<<=1) n2 += __shfl_xor(n2,off,32);
        vv[t] = s*(n2/(1.f+n2))*rsqrtf(n2+1e-9f);
    }
    __syncthreads();
    if (t < 64){
        int p = t>>3, c = t&7;
        float a = 0.f;
        for (int e=0;e<32;++e) a += pooled[p*256+c*32+e]*vv[c*32+e];
        bbs[t] = a;
    }
    __syncthreads();
    if (t < 64){
        int p = t>>3;
        float mx = -1e30f;
        for (int j=0;j<8;++j) mx = fmaxf(mx, bbs[p*8+j]);
        float sum = 0.f;
        for (int j=0;j<8;++j) sum += __expf(bbs[p*8+j]-mx);
        ccs[t] = __expf(bbs[t]-mx)/sum;
    }
    __syncthreads();
    {
        int c = t>>5;
        float s = 0.f;
        for (int p=0;p<8;++p) s += ccs[p*8+c]*pooled[p*256 + t];
        float n2 = s*s;
#pragma unroll
        for (int off=1; off<32; off<<=1) n2 += __shfl_xor(n2,off,32);
        vv[t] = s*(n2/(1.f+n2))*rsqrtf(n2+1e-9f);
    }
    __syncthreads();
    if (t < 8){
        float a = 0.f;
        for (int j=0;j<16;++j) a += vv[t*32+j]*aW[j];
        lg[t] = a + ab[0];
    }
    __syncthreads();
    if (t < 8){
        float mx = -1e30f;
        for (int j=0;j<8;++j) mx = fmaxf(mx, lg[j]);
        float sum = 0.f;
        for (int j=0;j<8;++j) sum += __expf(lg[j]-mx);
        aws[t] = __expf(lg[t]-mx)/sum;
    }
    __syncthreads();
    if (t < 32){
        float a = 0.f;
        for (int c=0;c<8;++c) a += aws[c]*vv[c*32+t];
        wcs[t] = a;
    }
    __syncthreads();
    if (t < 64){
        float a = 0.f;
        for (int e=0;e<32;++e) a += wcs[e]*pW1[e*64+t];
        h1[t] = silu_((a+pb1[t])*pg1[t]+pbe1[t]);
    }
    __syncthreads();
    if (t < 32){
        float a = 0.f;
        for (int j=0;j<64;++j) a += h1[j]*pW2[j*32+t];
        h2[t] = silu_((a+pb2[t])*pg2[t]+pbe2[t]);
    }
    __syncthreads();
    if (t == 0){
        float a = 0.f;
        for (int j=0;j<32;++j) a += h2[j]*pW3[j];
        a += pb3[0];
        if (!finite_(a)) a = 999.f;
        out[b] = a;
    }
}

__global__ void sentinel_k(float* __restrict__ out, float v){
    out[threadIdx.x] = v;
}

// ---------------- host side ----------------
extern "C" void kernel_launch(void* const* d_in, const int* in_sizes, int n_in,
                              void* d_out, int out_size, void* d_ws, size_t ws_size,
                              hipStream_t stream)
{
    (void)in_sizes; (void)n_in; (void)out_size;
    const float* x    = (const float*)d_in[0];
    const float* eat  = (const float*)d_in[1];
    const float* pos  = (const float*)d_in[2];
    const int*  eidx  = (const int*)d_in[3];
    const int*  batch = (const int*)d_in[4];
    const float* neW1=(const float*)d_in[5],  *neb1=(const float*)d_in[6],
               * neg1=(const float*)d_in[7],  *nebe1=(const float*)d_in[8];
    const float* neW2=(const float*)d_in[9],  *neb2=(const float*)d_in[10],
               * neg2=(const float*)d_in[11], *nebe2=(const float*)d_in[12];
    const float* eeW1=(const float*)d_in[13], *eeb1=(const float*)d_in[14];
    const float* eeW2=(const float*)d_in[15], *eeb2=(const float*)d_in[16];
    const float* ivW =(const float*)d_in[17], *ivb =(const float*)d_in[18];
    const float* cWma=(const float*)d_in[19], *cWmb=(const float*)d_in[20],
               * cWme=(const float*)d_in[21], *cbm =(const float*)d_in[22];
    const float* cWsx=(const float*)d_in[23], *cWsa=(const float*)d_in[24],
               * cbs =(const float*)d_in[25];
    const float* cWv1=(const float*)d_in[26], *cbv1=(const float*)d_in[27],
               * cWv2=(const float*)d_in[28], *cbv2=(const float*)d_in[29];
    const float* lng =(const float*)d_in[30], *lnb =(const float*)d_in[31],
               * vsg =(const float*)d_in[32];
    const float* pcW =(const float*)d_in[33], *pcb =(const float*)d_in[34];
    const float* pvW =(const float*)d_in[35];
    const float* sW  =(const float*)d_in[36];
    const float* aW  =(const float*)d_in[37], *ab  =(const float*)d_in[38];
    const float* pW1 =(const float*)d_in[39], *pb1 =(const float*)d_in[40],
               * pg1 =(const float*)d_in[41], *pbe1=(const float*)d_in[42];
    const float* pW2 =(const float*)d_in[43], *pb2 =(const float*)d_in[44],
               * pg2 =(const float*)d_in[45], *pbe2=(const float*)d_in[46];
    const float* pW3 =(const float*)d_in[47], *pb3 =(const float*)d_in[48];

    const int* src = eidx;
    const int* dst = eidx + NE;

    char* wp = (char*)d_ws;
    auto alloc = [&](size_t bytes)->char*{
        char* p = wp;
        wp += (bytes + 255) & ~(size_t)255;
        return p;
    };
    bf16*  bufM  = (bf16*) alloc((size_t)ECM*HD*2);
    bf16*  bufG  = (bf16*) alloc((size_t)ECM*HD*2);
    float* xs    = (float*)alloc((size_t)NN*HD*4);
    float* xvA   = (float*)alloc((size_t)NN*3*HD*4);
    float* xvB   = (float*)alloc((size_t)NN*3*HD*4);
    bf16*  An    = (bf16*) alloc((size_t)NN*HD*2);
    bf16*  Bn    = (bf16*) alloc((size_t)NN*HD*2);
    float* smC   = (float*)alloc((size_t)CN*HD*4);
    float* mdC   = (float*)alloc((size_t)CN*3*HD*4);
    float* avC   = (float*)alloc((size_t)CN*3*HD*4);
    float* sdC   = (float*)alloc((size_t)CN*3*4);
    bf16*  WtH   = (bf16*) alloc((size_t)7*HD*HD*2);
    bf16*  WtL   = (bf16*) alloc((size_t)7*HD*HD*2);
    bf16*  W1h   = (bf16*) alloc((size_t)HD*64*2);
    bf16*  W1l   = (bf16*) alloc((size_t)HD*64*2);
    float* Up    = (float*)alloc((size_t)NB*PSL*HD*4);
    float* Ubuf  = (float*)alloc((size_t)NB*HD*4);
    int* rowptr  = (int*)alloc((size_t)(NN+1)*4);
    int* cnt     = (int*)alloc((size_t)NN*4);
    int* bsum    = (int*)alloc((size_t)256*4);
    int* elist   = (int*)alloc((size_t)NE*4);
    int* srcp    = (int*)alloc((size_t)NE*4);
    int* dstp    = (int*)alloc((size_t)NE*4);
    int* gptr    = (int*)alloc((size_t)(NB+1)*4);
    size_t used  = (size_t)(wp - (char*)d_ws);   // ~249 MiB

    if (used > ws_size){
        sentinel_k<<<1, NB, 0, stream>>>((float*)d_out, -1.f - (float)(ws_size >> 20));
        return;
    }
    float* tmpF = xvB;
    bf16*  ubuf = An;
    float* Pf   = xvA;
    // nu-stage GEMM outputs overlay bufM/bufG (dead between scatter_c(c) and edge_pipe(c+1)):
    float* gF  = (float*)bufM;
    float* swF = gF  + (size_t)3*CN*HD;
    float* xwF = swF + (size_t)CN*HD;

    // ---- CSR + gptr + weight splits ----
    hipMemsetAsync(cnt, 0, (size_t)NN*4, stream);
    hist_kernel<<<(NE+255)/256, 256, 0, stream>>>(dst, cnt, NE, NN);
    const int SBLK = (NN+255)/256;   // 196 blocks
    scan_blk<<<SBLK, 256, 0, stream>>>(cnt, rowptr, bsum, NN);
    scan_bsum<<<1, 256, 0, stream>>>(bsum, SBLK);
    scan_fix<<<SBLK, 256, 0, stream>>>(rowptr, bsum, NN);
    hipMemsetAsync(cnt, 0, (size_t)NN*4, stream);
    fill_kernel<<<(NE+255)/256, 256, 0, stream>>>(src, dst, rowptr, cnt, elist, srcp, dstp, NE);
    gptr_kernel<<<(NN+255)/256, 256, 0, stream>>>(batch, gptr);
    wprep1<<<32,256,0,stream>>>(eeW1, W1h, W1l);
    wprep<<<64,256,0,stream>>>(eeW2, WtH, WtL);
    for (int l=0;l<3;++l){
        wprep<<<64,256,0,stream>>>(cWme + (size_t)l*HD*HD, WtH + (size_t)(1+l)*HD*HD,
                                   WtL + (size_t)(1+l)*HD*HD);
        wprep<<<64,256,0,stream>>>(cWv1 + (size_t)l*HD*HD, WtH + (size_t)(4+l)*HD*HD,
                                   WtL + (size_t)(4+l)*HD*HD);
    }

    const int GN = (NN+63)/64;
    const int GE = ECM/64;
    const int G3 = ((3*CN+63)/64) + 2*((CN+63)/64);

    // ---- node embeddings ----
    gemmk<M_BNSILU><<<GN,256,0,stream>>>(x, neW1, neb1, neg1, nebe1, tmpF, 0, NN, 92);
    gemmk<M_BNSILU><<<GN,256,0,stream>>>(tmpF, neW2, neb2, neg2, nebe2, xs, 0, NN, 128);
    gemmk<M_BIAS><<<GN,256,0,stream>>>(xs, ivW, ivb, nullptr, nullptr, tmpF, 0, NN, 128);
    xv_init<<<NN, 128, 0, stream>>>(tmpF, pos, xvA);

    // ---- message-passing layers ----
    float* xvO = xvA;
    float* xvN = xvB;
    for (int l=0; l<3; ++l){
        const float* Wma = cWma + (size_t)l*HD*HD;
        const float* Wmb = cWmb + (size_t)l*HD*HD;
        const float* bm  = cbm  + (size_t)l*HD;
        const float* Wsx = cWsx + (size_t)l*HD*HD;
        const float* Wsa = cWsa + (size_t)l*HD*HD;
        const float* bs  = cbs  + (size_t)l*HD;
        const float* bv1 = cbv1 + (size_t)l*HD;
        const float* Wv2 = cWv2 + (size_t)l*HD*HD;
        const float* bv2 = cbv2 + (size_t)l*HD;
        const bf16* Wmeh = WtH + (size_t)(1+l)*HD*HD;
        const bf16* Wmel = WtL + (size_t)(1+l)*HD*HD;
        const bf16* Wv1h = WtH + (size_t)(4+l)*HD*HD;
        const bf16* Wv1l = WtL + (size_t)(4+l)*HD*HD;

        gemmk<M_PLAIN><<<GN,256,0,stream>>>(xs, Wma, nullptr, nullptr, nullptr, An, 1, NN, 128);
        gemmk<M_PLAIN><<<GN,256,0,stream>>>(xs, Wmb, nullptr, nullptr, nullptr, Bn, 1, NN, 128);

        for (int c=0; c<NCH; ++c){
            int n0 = c*CN, n1 = n0+CN;
            edge_pipe<<<GE,256,0,stream>>>(eat, elist, srcp, dstp,
                                           W1h, W1l, eeb1,
                                           WtH, WtL, eeb2,
                                           Wmeh, Wmel, bm,
                                           An, Bn,
                                           Wv1h, Wv1l, bv1,
                                           rowptr, n0, n1, bufM, bufG);
            scatter_c<<<CN,128,0,stream>>>(rowptr, srcp, pos, bufM, bufG, xvO,
                                           smC, mdC, avC, sdC, n0, n1);
            gemm3<<<G3,256,0,stream>>>(mdC, Wv2, gF, 3*CN,
                                       smC, Wsa, swF, CN,
                                       xs + (size_t)n0*HD, Wsx, xwF, CN);
            nu_lite<<<CN,128,0,stream>>>(gF, swF, xwF, avC, sdC,
                                         xvO, xvN, xs,
                                         bv2, bs,
                                         lng + (size_t)l*HD, lnb + (size_t)l*HD,
                                         vsg + (size_t)l*HD, l>0 ? 1 : 0, n0, n1);
        }
        float* t = xvO; xvO = xvN; xvN = t;
    }

    // ---- capsules & head ----
    gemmk<M_BIAS><<<GN,256,0,stream>>>(xs, pcW, pcb, nullptr, nullptr, Pf, 0, NN, 128);
    capsule2<<<12500/4, 256, 0, stream>>>(Pf, xvO, pvW, ubuf);
    pool1<<<NB*PSL, 128, 0, stream>>>(gptr, ubuf, Up);
    pool2<<<NB, 128, 0, stream>>>(Up, Ubuf);
    graph_head<<<NB, 256, 0, stream>>>(Ubuf, sW, aW, ab,
                                       pW1, pb1, pg1, pbe1,
                                       pW2, pb2, pg2, pbe2,
                                       pW3, pb3, (float*)d_out);
}